// Round 6
// baseline (7003.398 us; speedup 1.0000x reference)
//
#include <hip/hip_runtime.h>
#include <math.h>

#define NEGV (-100000.0f)
constexpr int Bn = 64, Sn = 512, En = 256, Hn = 256, HIDn = 512, Tn = 9;
constexpr int START_T = Tn - 2, STOP_T = Tn - 1;
constexpr int Mn = Bn * Sn; // 32768 rows

typedef unsigned int u32;
typedef unsigned short u16;
typedef short short8 __attribute__((ext_vector_type(8)));
typedef float f32x4 __attribute__((ext_vector_type(4)));

__device__ __forceinline__ float sigf(float x) { return 1.0f / (1.0f + __expf(-x)); }
__device__ __forceinline__ float tanh_f(float x) { return 2.0f / (1.0f + __expf(-2.0f * x)) - 1.0f; }
__device__ __forceinline__ u16 f2bf(float f) {
  u32 u = __float_as_uint(f);
  return (u16)((u + 0x7fffu + ((u >> 16) & 1u)) >> 16);
}
__device__ __forceinline__ float bflo(u32 u) { return __uint_as_float(u << 16); }
__device__ __forceinline__ float bfhi(u32 u) { return __uint_as_float(u & 0xffff0000u); }
__device__ __forceinline__ float b2f(u16 v) { return __uint_as_float((u32)v << 16); }

// ---------------- prep: bf16 packs. wih transposed [dir][k][1024]; whh in MFMA B-fragment order ----------------
// B-frag stream: wfrag[d][nq][kstep][ntile][lane] = uint4 (8 bf16). ntile = 4*gate + w;
// column n = lane&15 -> unit u = nq*64 + 16*w + (lane&15); row(gate) = gate*256 + ...; k = kstep*32 + (lane>>4)*8 + j.
__global__ void prep_kernel(const float* __restrict__ wih0, const float* __restrict__ whh0,
                            const float* __restrict__ bih0, const float* __restrict__ bhh0,
                            const float* __restrict__ wih1, const float* __restrict__ whh1,
                            const float* __restrict__ bih1, const float* __restrict__ bhh1,
                            u16* __restrict__ wih0t, u16* __restrict__ wih1t,
                            u16* __restrict__ wfrag0, u16* __restrict__ wfrag1,
                            float* __restrict__ bias0, float* __restrict__ bias1) {
  int tid = blockIdx.x * blockDim.x + threadIdx.x;
  int nth = gridDim.x * blockDim.x;
  for (int idx = tid; idx < 2 * 256 * 1024; idx += nth) {
    int d = idx >> 18, rem = idx & 262143, e = rem >> 10, r = rem & 1023;
    wih0t[idx] = f2bf(wih0[(d * 1024 + r) * 256 + e]);
  }
  for (int idx = tid; idx < 2 * 512 * 1024; idx += nth) {
    int d = idx >> 19, rem = idx & 524287, e = rem >> 10, r = rem & 1023;
    wih1t[idx] = f2bf(wih1[(d * 1024 + r) * 512 + e]);
  }
  // MFMA B fragments for both layers' Whh (each 2*4*8*16*64*8 = 524288 u16)
  for (int idx = tid; idx < 524288; idx += nth) {
    int j = idx & 7, lane = (idx >> 3) & 63, nt = (idx >> 9) & 15,
        ks = (idx >> 13) & 7, nq = (idx >> 16) & 3, d = (idx >> 18) & 1;
    int row = (nt >> 2) * 256 + nq * 64 + (nt & 3) * 16 + (lane & 15);
    int k = ks * 32 + ((lane >> 4) & 3) * 8 + j;
    wfrag0[idx] = f2bf(whh0[(d * 1024 + row) * 256 + k]);
    wfrag1[idx] = f2bf(whh1[(d * 1024 + row) * 256 + k]);
  }
  for (int idx = tid; idx < 2 * 1024; idx += nth) {
    bias0[idx] = bih0[idx] + bhh0[idx];
    bias1[idx] = bih1[idx] + bhh1[idx];
  }
}

// ---------------- input-projection GEMM: gx[dir][m][1024] = X[m] @ Wt[dir] + bias ----------------
template <int K, bool GATHER>
__global__ __launch_bounds__(256) void gemm_gx(
    const void* __restrict__ xsrc_v,
    const int* __restrict__ sent,
    const u16* __restrict__ wt,       // [2][K][1024] bf16
    const float* __restrict__ bias,   // [2][1024]
    u16* __restrict__ gx)             // [2*M][1024] bf16
{
  constexpr int BM = 64, BN = 64, BK = 32;
  __shared__ float Xs[BK][BM];
  __shared__ float Ws[BK][BN];
  const int tid = threadIdx.x;
  const int tx = tid & 15, ty = tid >> 4;
  const int n0 = blockIdx.x * BN;
  const int m0 = blockIdx.y * BM;
  const int dir = blockIdx.z;

  const int lrow = tid >> 3;
  const int lk = (tid & 7) * 4;
  const int wk = tid >> 3;
  const int wn = (tid & 7) * 8;

  float acc[4][4] = {};

  for (int k0 = 0; k0 < K; k0 += BK) {
#pragma unroll
    for (int rr = 0; rr < 2; ++rr) {
      int m = m0 + lrow + rr * 32;
      if constexpr (GATHER) {
        const float* xrow = (const float*)xsrc_v + (size_t)sent[m] * K;
        float4 v = *reinterpret_cast<const float4*>(xrow + k0 + lk);
        Xs[lk + 0][lrow + rr * 32] = v.x;
        Xs[lk + 1][lrow + rr * 32] = v.y;
        Xs[lk + 2][lrow + rr * 32] = v.z;
        Xs[lk + 3][lrow + rr * 32] = v.w;
      } else {
        const u16* xrow = (const u16*)xsrc_v + (size_t)m * K;
        uint2 v = *reinterpret_cast<const uint2*>(xrow + k0 + lk);
        Xs[lk + 0][lrow + rr * 32] = bflo(v.x);
        Xs[lk + 1][lrow + rr * 32] = bfhi(v.x);
        Xs[lk + 2][lrow + rr * 32] = bflo(v.y);
        Xs[lk + 3][lrow + rr * 32] = bfhi(v.y);
      }
    }
    {
      const u16* wp = wt + ((size_t)dir * K + k0 + wk) * 1024 + n0 + wn;
      uint4 wv = *reinterpret_cast<const uint4*>(wp);
      Ws[wk][wn + 0] = bflo(wv.x); Ws[wk][wn + 1] = bfhi(wv.x);
      Ws[wk][wn + 2] = bflo(wv.y); Ws[wk][wn + 3] = bfhi(wv.y);
      Ws[wk][wn + 4] = bflo(wv.z); Ws[wk][wn + 5] = bfhi(wv.z);
      Ws[wk][wn + 6] = bflo(wv.w); Ws[wk][wn + 7] = bfhi(wv.w);
    }
    __syncthreads();
#pragma unroll 8
    for (int k = 0; k < BK; ++k) {
      float4 a = *reinterpret_cast<const float4*>(&Xs[k][ty * 4]);
      float4 b = *reinterpret_cast<const float4*>(&Ws[k][tx * 4]);
      acc[0][0] += a.x * b.x; acc[0][1] += a.x * b.y; acc[0][2] += a.x * b.z; acc[0][3] += a.x * b.w;
      acc[1][0] += a.y * b.x; acc[1][1] += a.y * b.y; acc[1][2] += a.y * b.z; acc[1][3] += a.y * b.w;
      acc[2][0] += a.z * b.x; acc[2][1] += a.z * b.y; acc[2][2] += a.z * b.z; acc[2][3] += a.z * b.w;
      acc[3][0] += a.w * b.x; acc[3][1] += a.w * b.y; acc[3][2] += a.w * b.z; acc[3][3] += a.w * b.w;
    }
    __syncthreads();
  }

  float4 bv = *reinterpret_cast<const float4*>(&bias[dir * 1024 + n0 + tx * 4]);
#pragma unroll
  for (int i = 0; i < 4; ++i) {
    int m = m0 + ty * 4 + i;
    ushort4 sv;
    sv.x = f2bf(acc[i][0] + bv.x);
    sv.y = f2bf(acc[i][1] + bv.y);
    sv.z = f2bf(acc[i][2] + bv.z);
    sv.w = f2bf(acc[i][3] + bv.w);
    *reinterpret_cast<ushort4*>(gx + ((size_t)dir * Mn + m) * 1024 + n0 + tx * 4) = sv;
  }
}

// ---------------- MFMA recurrence: 32 WGs = 2 dir x 4 batch-groups(16) x 4 unit-quarters ----------------
// Per step: gates[16m x 256n] = h[16 x 256] @ WhhQuarter + gx. Cross-WG h exchange via device-scope
// atomics on hx (double-buffered) + release/acquire step counter per (dir,bg) group of 4 WGs.
__global__ __launch_bounds__(256) void lstm_recur_mfma(
    const uint4* __restrict__ wfrag,  // [2][4][8][16][64] uint4
    const u16* __restrict__ gx,       // [2*Mn][1024] bf16
    u16* __restrict__ hx,             // [2 slots][8 groups][256 u][16 m] bf16
    u32* __restrict__ ctr,            // [8]
    u16* __restrict__ out)            // [B][S][512] bf16
{
  __shared__ u16 Ah[16][264];         // h in A-fragment source layout [m][k=unit], row pad vs bank conflicts
  const int tid = threadIdx.x;
  const int l = tid & 63;
  const int w = tid >> 6;
  const int bg = blockIdx.x, nq = blockIdx.y, dir = blockIdx.z;
  const int g = dir * 4 + bg;
  u32* cg = ctr + g;
  const int m0 = ((l >> 4) & 3) * 4;
  const int col = l & 15;
  const int u = nq * 64 + 16 * w + col;   // this lane's unit (update phase)
  const uint4* wf = wfrag + ((size_t)(dir * 4 + nq)) * 8 * 16 * 64;
  float c[4] = {0.f, 0.f, 0.f, 0.f};

  for (int s = 0; s < Sn; ++s) {
    const int t = dir ? (Sn - 1 - s) : s;

    // gx loads (i,f,g,o x 4 batches), consumed after MFMA phase
    u16 gxv[4][4];
#pragma unroll
    for (int r = 0; r < 4; ++r) {
      const u16* p = gx + ((size_t)(dir * Mn + (bg * 16 + m0 + r) * Sn + t)) * 1024 + nq * 64 + 16 * w + col;
#pragma unroll
      for (int gi = 0; gi < 4; ++gi) gxv[gi][r] = p[gi * 256];
    }

    f32x4 acc[4];
#pragma unroll
    for (int gi = 0; gi < 4; ++gi) acc[gi] = (f32x4){0.f, 0.f, 0.f, 0.f};

    if (s > 0) {
      if (tid == 0) {
        u32 target = 4u * (u32)s;
        while (__hip_atomic_load(cg, __ATOMIC_ACQUIRE, __HIP_MEMORY_SCOPE_AGENT) < target)
          __builtin_amdgcn_s_sleep(2);
      }
      __syncthreads();
      // gather full h_{s-1} (all 256 units x 16 batches) into LDS A-layout
      {
        const u32* hp = (const u32*)hx + ((size_t)(((s - 1) & 1) * 8 + g) * 256 + tid) * 8;
        u32 hv[8];
#pragma unroll
        for (int i = 0; i < 8; ++i)
          hv[i] = __hip_atomic_load(hp + i, __ATOMIC_RELAXED, __HIP_MEMORY_SCOPE_AGENT);
#pragma unroll
        for (int m = 0; m < 16; ++m)
          Ah[m][tid] = (u16)(hv[m >> 1] >> ((m & 1) * 16));
      }
      __syncthreads();
      // MFMA: 8 k-steps x 4 gate-tiles
#pragma unroll
      for (int ks = 0; ks < 8; ++ks) {
        uint4 av = *reinterpret_cast<const uint4*>(&Ah[col][ks * 32 + ((l >> 4) & 3) * 8]);
        short8 a8 = __builtin_bit_cast(short8, av);
#pragma unroll
        for (int gi = 0; gi < 4; ++gi) {
          uint4 bv = wf[((size_t)ks * 16 + (4 * gi + w)) * 64 + l];
          acc[gi] = __builtin_amdgcn_mfma_f32_16x16x32_bf16(a8, __builtin_bit_cast(short8, bv), acc[gi], 0, 0, 0);
        }
      }
    }

    // lane-local LSTM update: 4 batches x 1 unit
    u16 hbf[4];
#pragma unroll
    for (int r = 0; r < 4; ++r) {
      float gi_ = acc[0][r] + b2f(gxv[0][r]);
      float gf_ = acc[1][r] + b2f(gxv[1][r]);
      float gg_ = acc[2][r] + b2f(gxv[2][r]);
      float go_ = acc[3][r] + b2f(gxv[3][r]);
      c[r] = sigf(gf_) * c[r] + sigf(gi_) * tanh_f(gg_);
      float h = sigf(go_) * tanh_f(c[r]);
      hbf[r] = f2bf(h);
      out[((size_t)(bg * 16 + m0 + r) * Sn + t) * HIDn + dir * Hn + u] = hbf[r];
    }
    {
      u32* hp = (u32*)hx + ((size_t)((s & 1) * 8 + g) * 256 + u) * 8 + (m0 >> 1);
      __hip_atomic_store(hp, (u32)hbf[0] | ((u32)hbf[1] << 16), __ATOMIC_RELAXED, __HIP_MEMORY_SCOPE_AGENT);
      __hip_atomic_store(hp + 1, (u32)hbf[2] | ((u32)hbf[3] << 16), __ATOMIC_RELAXED, __HIP_MEMORY_SCOPE_AGENT);
    }
    __syncthreads();  // drains vmcnt before barrier -> hx stores visible at coherent point
    if (tid == 0)
      __hip_atomic_fetch_add(cg, 1u, __ATOMIC_RELEASE, __HIP_MEMORY_SCOPE_AGENT);
  }
}

// ---------------- FC: one wave per (b,t), bf16 input rows ----------------
__global__ __launch_bounds__(64) void fc_kernel(const u16* __restrict__ out1,
                                                const float* __restrict__ fcw,
                                                const float* __restrict__ fcb,
                                                float* __restrict__ feats) {
  const int bs = blockIdx.x;
  const int l = threadIdx.x;
  const u16* row = out1 + (size_t)bs * HIDn;
  uint4 rv = *reinterpret_cast<const uint4*>(row + l * 8);
  float v[8];
  v[0] = bflo(rv.x); v[1] = bfhi(rv.x);
  v[2] = bflo(rv.y); v[3] = bfhi(rv.y);
  v[4] = bflo(rv.z); v[5] = bfhi(rv.z);
  v[6] = bflo(rv.w); v[7] = bfhi(rv.w);
#pragma unroll
  for (int tag = 0; tag < Tn; ++tag) {
    const float* w = fcw + tag * HIDn + l * 8;
    float4 w0 = *reinterpret_cast<const float4*>(w);
    float4 w1 = *reinterpret_cast<const float4*>(w + 4);
    float acc = v[0] * w0.x + v[1] * w0.y + v[2] * w0.z + v[3] * w0.w
              + v[4] * w1.x + v[5] * w1.y + v[6] * w1.z + v[7] * w1.w;
#pragma unroll
    for (int off = 32; off; off >>= 1) acc += __shfl_xor(acc, off);
    if (l == 0) feats[bs * Tn + tag] = acc + fcb[tag];
  }
}

// ---------------- CRF forward + gold, one wave per batch ----------------
__global__ __launch_bounds__(64) void crf_kernel(const float* __restrict__ feats,
                                                 const int* __restrict__ tags,
                                                 const int* __restrict__ lens,
                                                 const float* __restrict__ trans,
                                                 float* __restrict__ scores) {
  const int b = blockIdx.x;
  const int j = threadIdx.x;
  const int jj = j < Tn ? j : Tn - 1;
  const int len = lens[b];

  float trc[Tn];
#pragma unroll
  for (int i = 0; i < Tn; ++i) trc[i] = trans[i * Tn + jj];
  const float trS = trans[jj * Tn + STOP_T];

  float alpha = (j == START_T) ? 0.0f : NEGV;
  const float* fb = feats + (size_t)b * Sn * Tn;

  for (int t = 0; t < Sn; ++t) {
    float f = (j < Tn) ? fb[t * Tn + j] : 0.0f;
    float v[Tn];
    float m = -3.0e38f;
#pragma unroll
    for (int i = 0; i < Tn; ++i) {
      float ai = __shfl(alpha, i);
      v[i] = ai + trc[i];
      m = fmaxf(m, v[i]);
    }
    float ssum = 0.0f;
#pragma unroll
    for (int i = 0; i < Tn; ++i) ssum += __expf(v[i] - m);
    float newa = m + __logf(ssum) + f;
    if (t < len && j < Tn) alpha = newa;
  }

  float val = (j < Tn) ? alpha + trS : -3.0e38f;
  float m = val;
#pragma unroll
  for (int off = 32; off; off >>= 1) m = fmaxf(m, __shfl_xor(m, off));
  float se = (j < Tn) ? __expf(val - m) : 0.0f;
#pragma unroll
  for (int off = 32; off; off >>= 1) se += __shfl_xor(se, off);
  float fscore = m + __logf(se);

  const int* tg = tags + b * Sn;
  float part = 0.0f;
  for (int q = 0; q < 8; ++q) {
    int s0 = j * 8 + q;
    if (s0 < Sn - 1 && (s0 + 1) < len) {
      int ta = tg[s0], tb = tg[s0 + 1];
      part += trans[ta * Tn + tb] + fb[s0 * Tn + tb];
    }
  }
#pragma unroll
  for (int off = 32; off; off >>= 1) part += __shfl_xor(part, off);

  if (j == 0) {
    int t0 = tg[0];
    int tl = tg[len - 1];
    float gold = trans[START_T * Tn + t0] + fb[0 * Tn + t0] + part + trans[tl * Tn + STOP_T];
    scores[b] = fscore - gold;
  }
}

__global__ void finalize_kernel(const float* __restrict__ scores, float* __restrict__ out) {
  int l = threadIdx.x;
  float v = scores[l];
#pragma unroll
  for (int off = 32; off; off >>= 1) v += __shfl_xor(v, off);
  if (l == 0) out[0] = v / 64.0f;
}

extern "C" void kernel_launch(void* const* d_in, const int* in_sizes, int n_in,
                              void* d_out, int out_size, void* d_ws, size_t ws_size,
                              hipStream_t stream) {
  const int* sent = (const int*)d_in[0];
  const int* tags = (const int*)d_in[1];
  const int* lens = (const int*)d_in[2];
  const float* emb = (const float*)d_in[3];
  const float* wih0 = (const float*)d_in[4];
  const float* whh0 = (const float*)d_in[5];
  const float* bih0 = (const float*)d_in[6];
  const float* bhh0 = (const float*)d_in[7];
  const float* wih1 = (const float*)d_in[8];
  const float* whh1 = (const float*)d_in[9];
  const float* bih1 = (const float*)d_in[10];
  const float* bhh1 = (const float*)d_in[11];
  const float* fcw = (const float*)d_in[12];
  const float* fcb = (const float*)d_in[13];
  const float* trans = (const float*)d_in[14];

  // workspace layout (~173 MB; feats aliases gx — gx dead after recur1, fc runs later)
  char* ws = (char*)d_ws;
  u16* outb = (u16*)ws;                                  // 33,554,432 B
  u16* gx = (u16*)(ws + 33554432);                       // 134,217,728 B
  float* feats = (float*)gx;                             // aliases gx (1,179,648 B)
  char* p = ws + 33554432 + 134217728;
  float* scores = (float*)p;            p += 256;
  float* bias0 = (float*)p;             p += 8192;
  float* bias1 = (float*)p;             p += 8192;
  u16* wih0t = (u16*)p;                 p += 1048576;
  u16* wih1t = (u16*)p;                 p += 2097152;
  u16* wfrag0 = (u16*)p;                p += 1048576;
  u16* wfrag1 = (u16*)p;                p += 1048576;
  u16* hx = (u16*)p;                    p += 131072;     // [2][8][256][16] bf16
  u32* ctr = (u32*)p;                   p += 64;         // [16]

  hipMemsetAsync(ctr, 0, 64, stream);

  prep_kernel<<<2048, 256, 0, stream>>>(wih0, whh0, bih0, bhh0, wih1, whh1, bih1, bhh1,
                                        wih0t, wih1t, wfrag0, wfrag1, bias0, bias1);

  dim3 ggrid(1024 / 64, Mn / 64, 2);
  dim3 rgrid(4, 4, 2); // bg, nq, dir
  gemm_gx<256, true><<<ggrid, 256, 0, stream>>>(emb, sent, wih0t, bias0, gx);
  lstm_recur_mfma<<<rgrid, 256, 0, stream>>>((const uint4*)wfrag0, gx, hx, ctr, outb);
  gemm_gx<512, false><<<ggrid, 256, 0, stream>>>(outb, nullptr, wih1t, bias1, gx);
  lstm_recur_mfma<<<rgrid, 256, 0, stream>>>((const uint4*)wfrag1, gx, hx, ctr + 8, outb);

  fc_kernel<<<Mn, 64, 0, stream>>>(outb, fcw, fcb, feats);
  crf_kernel<<<Bn, 64, 0, stream>>>(feats, tags, lens, trans, scores);
  finalize_kernel<<<1, 64, 0, stream>>>(scores, (float*)d_out);
}

// Round 7
// 6779.085 us; speedup vs baseline: 1.0331x; 1.0331x over previous
//
#include <hip/hip_runtime.h>
#include <math.h>

#define NEGV (-100000.0f)
constexpr int Bn = 64, Sn = 512, En = 256, Hn = 256, HIDn = 512, Tn = 9;
constexpr int START_T = Tn - 2, STOP_T = Tn - 1;
constexpr int Mn = Bn * Sn; // 32768 rows

typedef unsigned int u32;
typedef unsigned short u16;
typedef unsigned long long u64;
typedef short short8 __attribute__((ext_vector_type(8)));
typedef float f32x4 __attribute__((ext_vector_type(4)));

__device__ __forceinline__ float sigf(float x) { return 1.0f / (1.0f + __expf(-x)); }
__device__ __forceinline__ float tanh_f(float x) { return 2.0f / (1.0f + __expf(-2.0f * x)) - 1.0f; }
__device__ __forceinline__ u16 f2bf(float f) {
  u32 u = __float_as_uint(f);
  return (u16)((u + 0x7fffu + ((u >> 16) & 1u)) >> 16);
}
__device__ __forceinline__ float bflo(u32 u) { return __uint_as_float(u << 16); }
__device__ __forceinline__ float bfhi(u32 u) { return __uint_as_float(u & 0xffff0000u); }
__device__ __forceinline__ float b2f(u16 v) { return __uint_as_float((u32)v << 16); }

// ---------------- prep: bf16 packs. wih transposed [dir][k][1024]; whh in MFMA B-fragment order ----------------
__global__ void prep_kernel(const float* __restrict__ wih0, const float* __restrict__ whh0,
                            const float* __restrict__ bih0, const float* __restrict__ bhh0,
                            const float* __restrict__ wih1, const float* __restrict__ whh1,
                            const float* __restrict__ bih1, const float* __restrict__ bhh1,
                            u16* __restrict__ wih0t, u16* __restrict__ wih1t,
                            u16* __restrict__ wfrag0, u16* __restrict__ wfrag1,
                            float* __restrict__ bias0, float* __restrict__ bias1) {
  int tid = blockIdx.x * blockDim.x + threadIdx.x;
  int nth = gridDim.x * blockDim.x;
  for (int idx = tid; idx < 2 * 256 * 1024; idx += nth) {
    int d = idx >> 18, rem = idx & 262143, e = rem >> 10, r = rem & 1023;
    wih0t[idx] = f2bf(wih0[(d * 1024 + r) * 256 + e]);
  }
  for (int idx = tid; idx < 2 * 512 * 1024; idx += nth) {
    int d = idx >> 19, rem = idx & 524287, e = rem >> 10, r = rem & 1023;
    wih1t[idx] = f2bf(wih1[(d * 1024 + r) * 512 + e]);
  }
  // MFMA B fragments: wfrag[d][nq][ks][nt][lane][j]; nt = 4*gate + w
  for (int idx = tid; idx < 524288; idx += nth) {
    int j = idx & 7, lane = (idx >> 3) & 63, nt = (idx >> 9) & 15,
        ks = (idx >> 13) & 7, nq = (idx >> 16) & 3, d = (idx >> 18) & 1;
    int row = (nt >> 2) * 256 + nq * 64 + (nt & 3) * 16 + (lane & 15);
    int k = ks * 32 + ((lane >> 4) & 3) * 8 + j;
    wfrag0[idx] = f2bf(whh0[(d * 1024 + row) * 256 + k]);
    wfrag1[idx] = f2bf(whh1[(d * 1024 + row) * 256 + k]);
  }
  for (int idx = tid; idx < 2 * 1024; idx += nth) {
    bias0[idx] = bih0[idx] + bhh0[idx];
    bias1[idx] = bih1[idx] + bhh1[idx];
  }
}

// ---------------- input-projection GEMM: gx[dir][m][1024] = X[m] @ Wt[dir] + bias ----------------
template <int K, bool GATHER>
__global__ __launch_bounds__(256) void gemm_gx(
    const void* __restrict__ xsrc_v,
    const int* __restrict__ sent,
    const u16* __restrict__ wt,       // [2][K][1024] bf16
    const float* __restrict__ bias,   // [2][1024]
    u16* __restrict__ gx)             // [2*M][1024] bf16
{
  constexpr int BM = 64, BN = 64, BK = 32;
  __shared__ float Xs[BK][BM];
  __shared__ float Ws[BK][BN];
  const int tid = threadIdx.x;
  const int tx = tid & 15, ty = tid >> 4;
  const int n0 = blockIdx.x * BN;
  const int m0 = blockIdx.y * BM;
  const int dir = blockIdx.z;

  const int lrow = tid >> 3;
  const int lk = (tid & 7) * 4;
  const int wk = tid >> 3;
  const int wn = (tid & 7) * 8;

  float acc[4][4] = {};

  for (int k0 = 0; k0 < K; k0 += BK) {
#pragma unroll
    for (int rr = 0; rr < 2; ++rr) {
      int m = m0 + lrow + rr * 32;
      if constexpr (GATHER) {
        const float* xrow = (const float*)xsrc_v + (size_t)sent[m] * K;
        float4 v = *reinterpret_cast<const float4*>(xrow + k0 + lk);
        Xs[lk + 0][lrow + rr * 32] = v.x;
        Xs[lk + 1][lrow + rr * 32] = v.y;
        Xs[lk + 2][lrow + rr * 32] = v.z;
        Xs[lk + 3][lrow + rr * 32] = v.w;
      } else {
        const u16* xrow = (const u16*)xsrc_v + (size_t)m * K;
        uint2 v = *reinterpret_cast<const uint2*>(xrow + k0 + lk);
        Xs[lk + 0][lrow + rr * 32] = bflo(v.x);
        Xs[lk + 1][lrow + rr * 32] = bfhi(v.x);
        Xs[lk + 2][lrow + rr * 32] = bflo(v.y);
        Xs[lk + 3][lrow + rr * 32] = bfhi(v.y);
      }
    }
    {
      const u16* wp = wt + ((size_t)dir * K + k0 + wk) * 1024 + n0 + wn;
      uint4 wv = *reinterpret_cast<const uint4*>(wp);
      Ws[wk][wn + 0] = bflo(wv.x); Ws[wk][wn + 1] = bfhi(wv.x);
      Ws[wk][wn + 2] = bflo(wv.y); Ws[wk][wn + 3] = bfhi(wv.y);
      Ws[wk][wn + 4] = bflo(wv.z); Ws[wk][wn + 5] = bfhi(wv.z);
      Ws[wk][wn + 6] = bflo(wv.w); Ws[wk][wn + 7] = bfhi(wv.w);
    }
    __syncthreads();
#pragma unroll 8
    for (int k = 0; k < BK; ++k) {
      float4 a = *reinterpret_cast<const float4*>(&Xs[k][ty * 4]);
      float4 b = *reinterpret_cast<const float4*>(&Ws[k][tx * 4]);
      acc[0][0] += a.x * b.x; acc[0][1] += a.x * b.y; acc[0][2] += a.x * b.z; acc[0][3] += a.x * b.w;
      acc[1][0] += a.y * b.x; acc[1][1] += a.y * b.y; acc[1][2] += a.y * b.z; acc[1][3] += a.y * b.w;
      acc[2][0] += a.z * b.x; acc[2][1] += a.z * b.y; acc[2][2] += a.z * b.z; acc[2][3] += a.z * b.w;
      acc[3][0] += a.w * b.x; acc[3][1] += a.w * b.y; acc[3][2] += a.w * b.z; acc[3][3] += a.w * b.w;
    }
    __syncthreads();
  }

  float4 bv = *reinterpret_cast<const float4*>(&bias[dir * 1024 + n0 + tx * 4]);
#pragma unroll
  for (int i = 0; i < 4; ++i) {
    int m = m0 + ty * 4 + i;
    ushort4 sv;
    sv.x = f2bf(acc[i][0] + bv.x);
    sv.y = f2bf(acc[i][1] + bv.y);
    sv.z = f2bf(acc[i][2] + bv.z);
    sv.w = f2bf(acc[i][3] + bv.w);
    *reinterpret_cast<ushort4*>(gx + ((size_t)dir * Mn + m) * 1024 + n0 + tx * 4) = sv;
  }
}

// ---------------- MFMA recurrence v2: same-XCD groups, wave-parallel per-quarter flags ----------------
// 32 WGs, 1-D grid: g = bid&7 (dir*4+bg), nq = bid>>3. Group-mates (fixed g) all ≡ g (mod 8) -> same XCD.
// Per step: WG (g,nq) computes units [nq*64,(nq+1)*64) for 16 batches via 16x16x32 MFMA.
// h exchange: hx[slot][g][256 u][4 u64]; flag[g][q] (128B-padded) = steps completed by WG (g,q).
__global__ __launch_bounds__(256) void lstm_recur_mfma(
    const uint4* __restrict__ wfrag,  // [2][4][8][16][64] uint4
    const u16* __restrict__ gx,       // [2*Mn][1024] bf16
    u64* __restrict__ hx,             // [2][8][256][4] u64
    u32* __restrict__ flags,          // [8][4] stride-32 u32
    u16* __restrict__ out)            // [B][S][512] bf16
{
  __shared__ u16 Ah[16][258];         // h in A-source layout [m][k=unit]
  const int tid = threadIdx.x;
  const int l = tid & 63;
  const int w = tid >> 6;             // wave id == quarter this wave consumes
  const int bid = blockIdx.x;
  const int g = bid & 7;
  const int nq = bid >> 3;
  const int dir = g >> 2, bg = g & 3;
  const int m0 = ((l >> 4) & 3) * 4;
  const int col = l & 15;
  const int u = nq * 64 + 16 * w + col;   // unit owned in update phase
  const uint4* wf = wfrag + ((size_t)(dir * 4 + nq)) * 8 * 16 * 64;
  u32* myflag = flags + (g * 4 + nq) * 32;
  u32* qflag = flags + (g * 4 + w) * 32;
  float c[4] = {0.f, 0.f, 0.f, 0.f};

  for (int s = 0; s < Sn; ++s) {
    const int t = dir ? (Sn - 1 - s) : s;

    // issue gx loads early (consumed in update phase)
    u16 gxv[4][4];
#pragma unroll
    for (int r = 0; r < 4; ++r) {
      const u16* p = gx + ((size_t)(dir * Mn + (bg * 16 + m0 + r) * Sn + t)) * 1024 + u;
#pragma unroll
      for (int gi = 0; gi < 4; ++gi) gxv[gi][r] = p[gi * 256];
    }

    f32x4 acc[4];
#pragma unroll
    for (int gi = 0; gi < 4; ++gi) acc[gi] = (f32x4){0.f, 0.f, 0.f, 0.f};

    if (s > 0) {
      // wave w: wait for quarter w of h_{s-1}, then load & scatter it
      while (__hip_atomic_load(qflag, __ATOMIC_ACQUIRE, __HIP_MEMORY_SCOPE_AGENT) < (u32)s)
        __builtin_amdgcn_s_sleep(1);
      const u64* hp = hx + (((size_t)((s - 1) & 1) * 8 + g) * 256 + (w * 64 + l)) * 4;
      u64 hv[4];
#pragma unroll
      for (int i = 0; i < 4; ++i)
        hv[i] = __hip_atomic_load(hp + i, __ATOMIC_RELAXED, __HIP_MEMORY_SCOPE_AGENT);
#pragma unroll
      for (int m = 0; m < 16; ++m)
        Ah[m][w * 64 + l] = (u16)(hv[m >> 2] >> ((m & 3) * 16));
      __syncthreads();
#pragma unroll
      for (int ks = 0; ks < 8; ++ks) {
        uint4 av = *reinterpret_cast<const uint4*>(&Ah[col][ks * 32 + ((l >> 4) & 3) * 8]);
        short8 a8 = __builtin_bit_cast(short8, av);
#pragma unroll
        for (int gi = 0; gi < 4; ++gi) {
          uint4 bv = wf[((size_t)ks * 16 + (4 * gi + w)) * 64 + l];
          acc[gi] = __builtin_amdgcn_mfma_f32_16x16x32_bf16(a8, __builtin_bit_cast(short8, bv), acc[gi], 0, 0, 0);
        }
      }
    }

    // lane-local LSTM update: 4 batches x 1 unit
    u16 hbf[4];
#pragma unroll
    for (int r = 0; r < 4; ++r) {
      float gi_ = acc[0][r] + b2f(gxv[0][r]);
      float gf_ = acc[1][r] + b2f(gxv[1][r]);
      float gg_ = acc[2][r] + b2f(gxv[2][r]);
      float go_ = acc[3][r] + b2f(gxv[3][r]);
      c[r] = sigf(gf_) * c[r] + sigf(gi_) * tanh_f(gg_);
      float h = sigf(go_) * tanh_f(c[r]);
      hbf[r] = f2bf(h);
      out[((size_t)(bg * 16 + m0 + r) * Sn + t) * HIDn + dir * Hn + u] = hbf[r];
    }
    {
      u64 hpack = (u64)hbf[0] | ((u64)hbf[1] << 16) | ((u64)hbf[2] << 32) | ((u64)hbf[3] << 48);
      u64* hp = hx + (((size_t)(s & 1) * 8 + g) * 256 + u) * 4 + (m0 >> 2);
      __hip_atomic_store(hp, hpack, __ATOMIC_RELAXED, __HIP_MEMORY_SCOPE_AGENT);
    }
    __syncthreads();  // compiler drains vmcnt before s_barrier -> all h stores at coherent point
    if (tid == 0)
      __hip_atomic_store(myflag, (u32)(s + 1), __ATOMIC_RELEASE, __HIP_MEMORY_SCOPE_AGENT);
  }
}

// ---------------- FC: one wave per (b,t), bf16 input rows ----------------
__global__ __launch_bounds__(64) void fc_kernel(const u16* __restrict__ out1,
                                                const float* __restrict__ fcw,
                                                const float* __restrict__ fcb,
                                                float* __restrict__ feats) {
  const int bs = blockIdx.x;
  const int l = threadIdx.x;
  const u16* row = out1 + (size_t)bs * HIDn;
  uint4 rv = *reinterpret_cast<const uint4*>(row + l * 8);
  float v[8];
  v[0] = bflo(rv.x); v[1] = bfhi(rv.x);
  v[2] = bflo(rv.y); v[3] = bfhi(rv.y);
  v[4] = bflo(rv.z); v[5] = bfhi(rv.z);
  v[6] = bflo(rv.w); v[7] = bfhi(rv.w);
#pragma unroll
  for (int tag = 0; tag < Tn; ++tag) {
    const float* w = fcw + tag * HIDn + l * 8;
    float4 w0 = *reinterpret_cast<const float4*>(w);
    float4 w1 = *reinterpret_cast<const float4*>(w + 4);
    float acc = v[0] * w0.x + v[1] * w0.y + v[2] * w0.z + v[3] * w0.w
              + v[4] * w1.x + v[5] * w1.y + v[6] * w1.z + v[7] * w1.w;
#pragma unroll
    for (int off = 32; off; off >>= 1) acc += __shfl_xor(acc, off);
    if (l == 0) feats[bs * Tn + tag] = acc + fcb[tag];
  }
}

// ---------------- CRF forward + gold, one wave per batch ----------------
__global__ __launch_bounds__(64) void crf_kernel(const float* __restrict__ feats,
                                                 const int* __restrict__ tags,
                                                 const int* __restrict__ lens,
                                                 const float* __restrict__ trans,
                                                 float* __restrict__ scores) {
  const int b = blockIdx.x;
  const int j = threadIdx.x;
  const int jj = j < Tn ? j : Tn - 1;
  const int len = lens[b];

  float trc[Tn];
#pragma unroll
  for (int i = 0; i < Tn; ++i) trc[i] = trans[i * Tn + jj];
  const float trS = trans[jj * Tn + STOP_T];

  float alpha = (j == START_T) ? 0.0f : NEGV;
  const float* fb = feats + (size_t)b * Sn * Tn;

  for (int t = 0; t < Sn; ++t) {
    float f = (j < Tn) ? fb[t * Tn + j] : 0.0f;
    float v[Tn];
    float m = -3.0e38f;
#pragma unroll
    for (int i = 0; i < Tn; ++i) {
      float ai = __shfl(alpha, i);
      v[i] = ai + trc[i];
      m = fmaxf(m, v[i]);
    }
    float ssum = 0.0f;
#pragma unroll
    for (int i = 0; i < Tn; ++i) ssum += __expf(v[i] - m);
    float newa = m + __logf(ssum) + f;
    if (t < len && j < Tn) alpha = newa;
  }

  float val = (j < Tn) ? alpha + trS : -3.0e38f;
  float m = val;
#pragma unroll
  for (int off = 32; off; off >>= 1) m = fmaxf(m, __shfl_xor(m, off));
  float se = (j < Tn) ? __expf(val - m) : 0.0f;
#pragma unroll
  for (int off = 32; off; off >>= 1) se += __shfl_xor(se, off);
  float fscore = m + __logf(se);

  const int* tg = tags + b * Sn;
  float part = 0.0f;
  for (int q = 0; q < 8; ++q) {
    int s0 = j * 8 + q;
    if (s0 < Sn - 1 && (s0 + 1) < len) {
      int ta = tg[s0], tb = tg[s0 + 1];
      part += trans[ta * Tn + tb] + fb[s0 * Tn + tb];
    }
  }
#pragma unroll
  for (int off = 32; off; off >>= 1) part += __shfl_xor(part, off);

  if (j == 0) {
    int t0 = tg[0];
    int tl = tg[len - 1];
    float gold = trans[START_T * Tn + t0] + fb[0 * Tn + t0] + part + trans[tl * Tn + STOP_T];
    scores[b] = fscore - gold;
  }
}

__global__ void finalize_kernel(const float* __restrict__ scores, float* __restrict__ out) {
  int l = threadIdx.x;
  float v = scores[l];
#pragma unroll
  for (int off = 32; off; off >>= 1) v += __shfl_xor(v, off);
  if (l == 0) out[0] = v / 64.0f;
}

extern "C" void kernel_launch(void* const* d_in, const int* in_sizes, int n_in,
                              void* d_out, int out_size, void* d_ws, size_t ws_size,
                              hipStream_t stream) {
  const int* sent = (const int*)d_in[0];
  const int* tags = (const int*)d_in[1];
  const int* lens = (const int*)d_in[2];
  const float* emb = (const float*)d_in[3];
  const float* wih0 = (const float*)d_in[4];
  const float* whh0 = (const float*)d_in[5];
  const float* bih0 = (const float*)d_in[6];
  const float* bhh0 = (const float*)d_in[7];
  const float* wih1 = (const float*)d_in[8];
  const float* whh1 = (const float*)d_in[9];
  const float* bih1 = (const float*)d_in[10];
  const float* bhh1 = (const float*)d_in[11];
  const float* fcw = (const float*)d_in[12];
  const float* fcb = (const float*)d_in[13];
  const float* trans = (const float*)d_in[14];

  // workspace layout (~173 MB; feats aliases gx — gx dead before fc runs)
  char* ws = (char*)d_ws;
  u16* outb = (u16*)ws;                                  // 33,554,432 B
  u16* gx = (u16*)(ws + 33554432);                       // 134,217,728 B
  float* feats = (float*)gx;                             // aliases gx (1,179,648 B)
  char* p = ws + 33554432 + 134217728;
  float* scores = (float*)p;            p += 256;
  float* bias0 = (float*)p;             p += 8192;
  float* bias1 = (float*)p;             p += 8192;
  u16* wih0t = (u16*)p;                 p += 1048576;
  u16* wih1t = (u16*)p;                 p += 2097152;
  u16* wfrag0 = (u16*)p;                p += 1048576;
  u16* wfrag1 = (u16*)p;                p += 1048576;
  u64* hx = (u64*)p;                    p += 131072;     // [2][8][256][4] u64
  u32* flags = (u32*)p;                 p += 8192;       // 2 layers x [8][4] stride-32 u32

  hipMemsetAsync(flags, 0, 8192, stream);

  prep_kernel<<<2048, 256, 0, stream>>>(wih0, whh0, bih0, bhh0, wih1, whh1, bih1, bhh1,
                                        wih0t, wih1t, wfrag0, wfrag1, bias0, bias1);

  dim3 ggrid(1024 / 64, Mn / 64, 2);
  gemm_gx<256, true><<<ggrid, 256, 0, stream>>>(emb, sent, wih0t, bias0, gx);
  lstm_recur_mfma<<<32, 256, 0, stream>>>((const uint4*)wfrag0, gx, hx, flags, outb);
  gemm_gx<512, false><<<ggrid, 256, 0, stream>>>(outb, nullptr, wih1t, bias1, gx);
  lstm_recur_mfma<<<32, 256, 0, stream>>>((const uint4*)wfrag1, gx, hx, flags + 1024, outb);

  fc_kernel<<<Mn, 64, 0, stream>>>(outb, fcw, fcb, feats);
  crf_kernel<<<Bn, 64, 0, stream>>>(feats, tags, lens, trans, scores);
  finalize_kernel<<<1, 64, 0, stream>>>(scores, (float*)d_out);
}

// Round 8
// 4854.095 us; speedup vs baseline: 1.4428x; 1.3966x over previous
//
#include <hip/hip_runtime.h>
#include <math.h>

#define NEGV (-100000.0f)
constexpr int Bn = 64, Sn = 512, En = 256, Hn = 256, HIDn = 512, Tn = 9;
constexpr int START_T = Tn - 2, STOP_T = Tn - 1;
constexpr int Mn = Bn * Sn; // 32768 rows

typedef unsigned int u32;
typedef unsigned short u16;
typedef unsigned long long u64;
typedef short short8 __attribute__((ext_vector_type(8)));
typedef float f32x4 __attribute__((ext_vector_type(4)));

__device__ __forceinline__ float sigf(float x) { return 1.0f / (1.0f + __expf(-x)); }
__device__ __forceinline__ float tanh_f(float x) { return 2.0f / (1.0f + __expf(-2.0f * x)) - 1.0f; }
__device__ __forceinline__ u16 f2bf(float f) {
  u32 u = __float_as_uint(f);
  return (u16)((u + 0x7fffu + ((u >> 16) & 1u)) >> 16);
}
__device__ __forceinline__ float bflo(u32 u) { return __uint_as_float(u << 16); }
__device__ __forceinline__ float bfhi(u32 u) { return __uint_as_float(u & 0xffff0000u); }
__device__ __forceinline__ float b2f(u16 v) { return __uint_as_float((u32)v << 16); }

// ---------------- prep: bf16 packs. wih transposed [dir][k][1024]; whh in MFMA B-fragment order ----------------
__global__ void prep_kernel(const float* __restrict__ wih0, const float* __restrict__ whh0,
                            const float* __restrict__ bih0, const float* __restrict__ bhh0,
                            const float* __restrict__ wih1, const float* __restrict__ whh1,
                            const float* __restrict__ bih1, const float* __restrict__ bhh1,
                            u16* __restrict__ wih0t, u16* __restrict__ wih1t,
                            u16* __restrict__ wfrag0, u16* __restrict__ wfrag1,
                            float* __restrict__ bias0, float* __restrict__ bias1) {
  int tid = blockIdx.x * blockDim.x + threadIdx.x;
  int nth = gridDim.x * blockDim.x;
  for (int idx = tid; idx < 2 * 256 * 1024; idx += nth) {
    int d = idx >> 18, rem = idx & 262143, e = rem >> 10, r = rem & 1023;
    wih0t[idx] = f2bf(wih0[(d * 1024 + r) * 256 + e]);
  }
  for (int idx = tid; idx < 2 * 512 * 1024; idx += nth) {
    int d = idx >> 19, rem = idx & 524287, e = rem >> 10, r = rem & 1023;
    wih1t[idx] = f2bf(wih1[(d * 1024 + r) * 512 + e]);
  }
  // MFMA B fragments: wfrag[d][nq][ks][nt][lane][j]; nt = 4*gate + w
  for (int idx = tid; idx < 524288; idx += nth) {
    int j = idx & 7, lane = (idx >> 3) & 63, nt = (idx >> 9) & 15,
        ks = (idx >> 13) & 7, nq = (idx >> 16) & 3, d = (idx >> 18) & 1;
    int row = (nt >> 2) * 256 + nq * 64 + (nt & 3) * 16 + (lane & 15);
    int k = ks * 32 + ((lane >> 4) & 3) * 8 + j;
    wfrag0[idx] = f2bf(whh0[(d * 1024 + row) * 256 + k]);
    wfrag1[idx] = f2bf(whh1[(d * 1024 + row) * 256 + k]);
  }
  for (int idx = tid; idx < 2 * 1024; idx += nth) {
    bias0[idx] = bih0[idx] + bhh0[idx];
    bias1[idx] = bih1[idx] + bhh1[idx];
  }
}

// ---------------- input-projection GEMM: gx[dir][m][1024] = X[m] @ Wt[dir] + bias ----------------
template <int K, bool GATHER>
__global__ __launch_bounds__(256) void gemm_gx(
    const void* __restrict__ xsrc_v,
    const int* __restrict__ sent,
    const u16* __restrict__ wt,       // [2][K][1024] bf16
    const float* __restrict__ bias,   // [2][1024]
    u16* __restrict__ gx)             // [2*M][1024] bf16
{
  constexpr int BM = 64, BN = 64, BK = 32;
  __shared__ float Xs[BK][BM];
  __shared__ float Ws[BK][BN];
  const int tid = threadIdx.x;
  const int tx = tid & 15, ty = tid >> 4;
  const int n0 = blockIdx.x * BN;
  const int m0 = blockIdx.y * BM;
  const int dir = blockIdx.z;

  const int lrow = tid >> 3;
  const int lk = (tid & 7) * 4;
  const int wk = tid >> 3;
  const int wn = (tid & 7) * 8;

  float acc[4][4] = {};

  for (int k0 = 0; k0 < K; k0 += BK) {
#pragma unroll
    for (int rr = 0; rr < 2; ++rr) {
      int m = m0 + lrow + rr * 32;
      if constexpr (GATHER) {
        const float* xrow = (const float*)xsrc_v + (size_t)sent[m] * K;
        float4 v = *reinterpret_cast<const float4*>(xrow + k0 + lk);
        Xs[lk + 0][lrow + rr * 32] = v.x;
        Xs[lk + 1][lrow + rr * 32] = v.y;
        Xs[lk + 2][lrow + rr * 32] = v.z;
        Xs[lk + 3][lrow + rr * 32] = v.w;
      } else {
        const u16* xrow = (const u16*)xsrc_v + (size_t)m * K;
        uint2 v = *reinterpret_cast<const uint2*>(xrow + k0 + lk);
        Xs[lk + 0][lrow + rr * 32] = bflo(v.x);
        Xs[lk + 1][lrow + rr * 32] = bfhi(v.x);
        Xs[lk + 2][lrow + rr * 32] = bflo(v.y);
        Xs[lk + 3][lrow + rr * 32] = bfhi(v.y);
      }
    }
    {
      const u16* wp = wt + ((size_t)dir * K + k0 + wk) * 1024 + n0 + wn;
      uint4 wv = *reinterpret_cast<const uint4*>(wp);
      Ws[wk][wn + 0] = bflo(wv.x); Ws[wk][wn + 1] = bfhi(wv.x);
      Ws[wk][wn + 2] = bflo(wv.y); Ws[wk][wn + 3] = bfhi(wv.y);
      Ws[wk][wn + 4] = bflo(wv.z); Ws[wk][wn + 5] = bfhi(wv.z);
      Ws[wk][wn + 6] = bflo(wv.w); Ws[wk][wn + 7] = bfhi(wv.w);
    }
    __syncthreads();
#pragma unroll 8
    for (int k = 0; k < BK; ++k) {
      float4 a = *reinterpret_cast<const float4*>(&Xs[k][ty * 4]);
      float4 b = *reinterpret_cast<const float4*>(&Ws[k][tx * 4]);
      acc[0][0] += a.x * b.x; acc[0][1] += a.x * b.y; acc[0][2] += a.x * b.z; acc[0][3] += a.x * b.w;
      acc[1][0] += a.y * b.x; acc[1][1] += a.y * b.y; acc[1][2] += a.y * b.z; acc[1][3] += a.y * b.w;
      acc[2][0] += a.z * b.x; acc[2][1] += a.z * b.y; acc[2][2] += a.z * b.z; acc[2][3] += a.z * b.w;
      acc[3][0] += a.w * b.x; acc[3][1] += a.w * b.y; acc[3][2] += a.w * b.z; acc[3][3] += a.w * b.w;
    }
    __syncthreads();
  }

  float4 bv = *reinterpret_cast<const float4*>(&bias[dir * 1024 + n0 + tx * 4]);
#pragma unroll
  for (int i = 0; i < 4; ++i) {
    int m = m0 + ty * 4 + i;
    ushort4 sv;
    sv.x = f2bf(acc[i][0] + bv.x);
    sv.y = f2bf(acc[i][1] + bv.y);
    sv.z = f2bf(acc[i][2] + bv.z);
    sv.w = f2bf(acc[i][3] + bv.w);
    *reinterpret_cast<ushort4*>(gx + ((size_t)dir * Mn + m) * 1024 + n0 + tx * 4) = sv;
  }
}

// ---------------- MFMA recurrence v3: Whh in LDS, relaxed polls (no L2-invalidate storm) ----------------
// 32 WGs: g = bid&7 (dir*4+bg), nq = bid>>3. Per step: WG computes units [nq*64,(nq+1)*64) x 16 batches.
// h exchange: hx[slot][g][256 u][4 u64] in IC via relaxed agent atomics; flag[g][q] = steps completed.
// Poll uses RELAXED loads (sc1 -> IC, no buffer_inv); single RELEASE on flag store.
__global__ __launch_bounds__(256) void lstm_recur_mfma(
    const uint4* __restrict__ wfrag,  // [2][4][8][16][64] uint4
    const u16* __restrict__ gx,       // [2*Mn][1024] bf16
    u64* __restrict__ hx,             // [2][8][256][4] u64
    u32* __restrict__ flags,          // [8][4] stride-32 u32
    u16* __restrict__ out)            // [B][S][512] bf16
{
  __shared__ uint4 Bs[8192];          // whole Whh quarter in B-frag layout (128 KB)
  __shared__ u16 Ah[16][258];         // h in A-source layout [m][k=unit] (8.25 KB)
  const int tid = threadIdx.x;
  const int l = tid & 63;
  const int w = tid >> 6;             // wave id == quarter this wave consumes
  const int bid = blockIdx.x;
  const int g = bid & 7;
  const int nq = bid >> 3;
  const int dir = g >> 2, bg = g & 3;
  const int m0 = ((l >> 4) & 3) * 4;
  const int col = l & 15;
  const int u = nq * 64 + 16 * w + col;   // unit owned in update phase
  const uint4* wf = wfrag + ((size_t)(dir * 4 + nq)) * 8 * 16 * 64;
  u32* myflag = flags + (g * 4 + nq) * 32;
  u32* qflag = flags + (g * 4 + w) * 32;
  float c[4] = {0.f, 0.f, 0.f, 0.f};

  // stage the whole B-fragment block into LDS once (immune to cache invalidation)
  for (int i = 0; i < 32; ++i) Bs[tid + i * 256] = wf[tid + i * 256];
  __syncthreads();

  for (int s = 0; s < Sn; ++s) {
    const int t = dir ? (Sn - 1 - s) : s;

    // issue gx loads early (consumed in update phase)
    u16 gxv[4][4];
#pragma unroll
    for (int r = 0; r < 4; ++r) {
      const u16* p = gx + ((size_t)(dir * Mn + (bg * 16 + m0 + r) * Sn + t)) * 1024 + u;
#pragma unroll
      for (int gi = 0; gi < 4; ++gi) gxv[gi][r] = p[gi * 256];
    }

    f32x4 acc[4];
#pragma unroll
    for (int gi = 0; gi < 4; ++gi) acc[gi] = (f32x4){0.f, 0.f, 0.f, 0.f};

    if (s > 0) {
      // wave w: wait for quarter w of h_{s-1} (RELAXED poll -> no L2 invalidate per iteration)
      while (__hip_atomic_load(qflag, __ATOMIC_RELAXED, __HIP_MEMORY_SCOPE_AGENT) < (u32)s)
        __builtin_amdgcn_s_sleep(1);
      const u64* hp = hx + (((size_t)((s - 1) & 1) * 8 + g) * 256 + (w * 64 + l)) * 4;
      u64 hv[4];
#pragma unroll
      for (int i = 0; i < 4; ++i)
        hv[i] = __hip_atomic_load(hp + i, __ATOMIC_RELAXED, __HIP_MEMORY_SCOPE_AGENT);
#pragma unroll
      for (int m = 0; m < 16; ++m)
        Ah[m][w * 64 + l] = (u16)(hv[m >> 2] >> ((m & 3) * 16));
      __syncthreads();
#pragma unroll
      for (int ks = 0; ks < 8; ++ks) {
        uint4 av = *reinterpret_cast<const uint4*>(&Ah[col][ks * 32 + ((l >> 4) & 3) * 8]);
        short8 a8 = __builtin_bit_cast(short8, av);
#pragma unroll
        for (int gi = 0; gi < 4; ++gi) {
          uint4 bv = Bs[((size_t)ks * 16 + (4 * gi + w)) * 64 + l];
          acc[gi] = __builtin_amdgcn_mfma_f32_16x16x32_bf16(a8, __builtin_bit_cast(short8, bv), acc[gi], 0, 0, 0);
        }
      }
    }

    // lane-local LSTM update: 4 batches x 1 unit
    u16 hbf[4];
#pragma unroll
    for (int r = 0; r < 4; ++r) {
      float gi_ = acc[0][r] + b2f(gxv[0][r]);
      float gf_ = acc[1][r] + b2f(gxv[1][r]);
      float gg_ = acc[2][r] + b2f(gxv[2][r]);
      float go_ = acc[3][r] + b2f(gxv[3][r]);
      c[r] = sigf(gf_) * c[r] + sigf(gi_) * tanh_f(gg_);
      float h = sigf(go_) * tanh_f(c[r]);
      hbf[r] = f2bf(h);
    }
    {
      u64 hpack = (u64)hbf[0] | ((u64)hbf[1] << 16) | ((u64)hbf[2] << 32) | ((u64)hbf[3] << 48);
      u64* hp = hx + (((size_t)(s & 1) * 8 + g) * 256 + u) * 4 + (m0 >> 2);
      __hip_atomic_store(hp, hpack, __ATOMIC_RELAXED, __HIP_MEMORY_SCOPE_AGENT);
    }
    __syncthreads();  // drains vmcnt -> h stores visible at IC before flag
    if (tid == 0)
      __hip_atomic_store(myflag, (u32)(s + 1), __ATOMIC_RELEASE, __HIP_MEMORY_SCOPE_AGENT);
    // out stores AFTER the flag -> their drain overlaps next step's poll/load
#pragma unroll
    for (int r = 0; r < 4; ++r)
      out[((size_t)(bg * 16 + m0 + r) * Sn + t) * HIDn + dir * Hn + u] = hbf[r];
  }
}

// ---------------- FC: one wave per (b,t), bf16 input rows ----------------
__global__ __launch_bounds__(64) void fc_kernel(const u16* __restrict__ out1,
                                                const float* __restrict__ fcw,
                                                const float* __restrict__ fcb,
                                                float* __restrict__ feats) {
  const int bs = blockIdx.x;
  const int l = threadIdx.x;
  const u16* row = out1 + (size_t)bs * HIDn;
  uint4 rv = *reinterpret_cast<const uint4*>(row + l * 8);
  float v[8];
  v[0] = bflo(rv.x); v[1] = bfhi(rv.x);
  v[2] = bflo(rv.y); v[3] = bfhi(rv.y);
  v[4] = bflo(rv.z); v[5] = bfhi(rv.z);
  v[6] = bflo(rv.w); v[7] = bfhi(rv.w);
#pragma unroll
  for (int tag = 0; tag < Tn; ++tag) {
    const float* w = fcw + tag * HIDn + l * 8;
    float4 w0 = *reinterpret_cast<const float4*>(w);
    float4 w1 = *reinterpret_cast<const float4*>(w + 4);
    float acc = v[0] * w0.x + v[1] * w0.y + v[2] * w0.z + v[3] * w0.w
              + v[4] * w1.x + v[5] * w1.y + v[6] * w1.z + v[7] * w1.w;
#pragma unroll
    for (int off = 32; off; off >>= 1) acc += __shfl_xor(acc, off);
    if (l == 0) feats[bs * Tn + tag] = acc + fcb[tag];
  }
}

// ---------------- CRF forward + gold, one wave per batch ----------------
__global__ __launch_bounds__(64) void crf_kernel(const float* __restrict__ feats,
                                                 const int* __restrict__ tags,
                                                 const int* __restrict__ lens,
                                                 const float* __restrict__ trans,
                                                 float* __restrict__ scores) {
  const int b = blockIdx.x;
  const int j = threadIdx.x;
  const int jj = j < Tn ? j : Tn - 1;
  const int len = lens[b];

  float trc[Tn];
#pragma unroll
  for (int i = 0; i < Tn; ++i) trc[i] = trans[i * Tn + jj];
  const float trS = trans[jj * Tn + STOP_T];

  float alpha = (j == START_T) ? 0.0f : NEGV;
  const float* fb = feats + (size_t)b * Sn * Tn;

  for (int t = 0; t < Sn; ++t) {
    float f = (j < Tn) ? fb[t * Tn + j] : 0.0f;
    float v[Tn];
    float m = -3.0e38f;
#pragma unroll
    for (int i = 0; i < Tn; ++i) {
      float ai = __shfl(alpha, i);
      v[i] = ai + trc[i];
      m = fmaxf(m, v[i]);
    }
    float ssum = 0.0f;
#pragma unroll
    for (int i = 0; i < Tn; ++i) ssum += __expf(v[i] - m);
    float newa = m + __logf(ssum) + f;
    if (t < len && j < Tn) alpha = newa;
  }

  float val = (j < Tn) ? alpha + trS : -3.0e38f;
  float m = val;
#pragma unroll
  for (int off = 32; off; off >>= 1) m = fmaxf(m, __shfl_xor(m, off));
  float se = (j < Tn) ? __expf(val - m) : 0.0f;
#pragma unroll
  for (int off = 32; off; off >>= 1) se += __shfl_xor(se, off);
  float fscore = m + __logf(se);

  const int* tg = tags + b * Sn;
  float part = 0.0f;
  for (int q = 0; q < 8; ++q) {
    int s0 = j * 8 + q;
    if (s0 < Sn - 1 && (s0 + 1) < len) {
      int ta = tg[s0], tb = tg[s0 + 1];
      part += trans[ta * Tn + tb] + fb[s0 * Tn + tb];
    }
  }
#pragma unroll
  for (int off = 32; off; off >>= 1) part += __shfl_xor(part, off);

  if (j == 0) {
    int t0 = tg[0];
    int tl = tg[len - 1];
    float gold = trans[START_T * Tn + t0] + fb[0 * Tn + t0] + part + trans[tl * Tn + STOP_T];
    scores[b] = fscore - gold;
  }
}

__global__ void finalize_kernel(const float* __restrict__ scores, float* __restrict__ out) {
  int l = threadIdx.x;
  float v = scores[l];
#pragma unroll
  for (int off = 32; off; off >>= 1) v += __shfl_xor(v, off);
  if (l == 0) out[0] = v / 64.0f;
}

extern "C" void kernel_launch(void* const* d_in, const int* in_sizes, int n_in,
                              void* d_out, int out_size, void* d_ws, size_t ws_size,
                              hipStream_t stream) {
  const int* sent = (const int*)d_in[0];
  const int* tags = (const int*)d_in[1];
  const int* lens = (const int*)d_in[2];
  const float* emb = (const float*)d_in[3];
  const float* wih0 = (const float*)d_in[4];
  const float* whh0 = (const float*)d_in[5];
  const float* bih0 = (const float*)d_in[6];
  const float* bhh0 = (const float*)d_in[7];
  const float* wih1 = (const float*)d_in[8];
  const float* whh1 = (const float*)d_in[9];
  const float* bih1 = (const float*)d_in[10];
  const float* bhh1 = (const float*)d_in[11];
  const float* fcw = (const float*)d_in[12];
  const float* fcb = (const float*)d_in[13];
  const float* trans = (const float*)d_in[14];

  // workspace layout (~173 MB; feats aliases gx — gx dead before fc runs)
  char* ws = (char*)d_ws;
  u16* outb = (u16*)ws;                                  // 33,554,432 B
  u16* gx = (u16*)(ws + 33554432);                       // 134,217,728 B
  float* feats = (float*)gx;                             // aliases gx (1,179,648 B)
  char* p = ws + 33554432 + 134217728;
  float* scores = (float*)p;            p += 256;
  float* bias0 = (float*)p;             p += 8192;
  float* bias1 = (float*)p;             p += 8192;
  u16* wih0t = (u16*)p;                 p += 1048576;
  u16* wih1t = (u16*)p;                 p += 2097152;
  u16* wfrag0 = (u16*)p;                p += 1048576;
  u16* wfrag1 = (u16*)p;                p += 1048576;
  u64* hx = (u64*)p;                    p += 131072;     // [2][8][256][4] u64
  u32* flags = (u32*)p;                 p += 8192;       // 2 layers x [8][4] stride-32 u32

  hipMemsetAsync(flags, 0, 8192, stream);

  prep_kernel<<<2048, 256, 0, stream>>>(wih0, whh0, bih0, bhh0, wih1, whh1, bih1, bhh1,
                                        wih0t, wih1t, wfrag0, wfrag1, bias0, bias1);

  dim3 ggrid(1024 / 64, Mn / 64, 2);
  gemm_gx<256, true><<<ggrid, 256, 0, stream>>>(emb, sent, wih0t, bias0, gx);
  lstm_recur_mfma<<<32, 256, 0, stream>>>((const uint4*)wfrag0, gx, hx, flags, outb);
  gemm_gx<512, false><<<ggrid, 256, 0, stream>>>(outb, nullptr, wih1t, bias1, gx);
  lstm_recur_mfma<<<32, 256, 0, stream>>>((const uint4*)wfrag1, gx, hx, flags + 1024, outb);

  fc_kernel<<<Mn, 64, 0, stream>>>(outb, fcw, fcb, feats);
  crf_kernel<<<Bn, 64, 0, stream>>>(feats, tags, lens, trans, scores);
  finalize_kernel<<<1, 64, 0, stream>>>(scores, (float*)d_out);
}

// Round 9
// 4285.443 us; speedup vs baseline: 1.6342x; 1.1327x over previous
//
#include <hip/hip_runtime.h>
#include <math.h>

#define NEGV (-100000.0f)
constexpr int Bn = 64, Sn = 512, En = 256, Hn = 256, HIDn = 512, Tn = 9;
constexpr int START_T = Tn - 2, STOP_T = Tn - 1;
constexpr int Mn = Bn * Sn; // 32768 rows

typedef unsigned int u32;
typedef unsigned short u16;
typedef unsigned long long u64;
typedef short short8 __attribute__((ext_vector_type(8)));
typedef float f32x4 __attribute__((ext_vector_type(4)));

__device__ __forceinline__ float sigf(float x) { return 1.0f / (1.0f + __expf(-x)); }
__device__ __forceinline__ float tanh_f(float x) { return 2.0f / (1.0f + __expf(-2.0f * x)) - 1.0f; }
__device__ __forceinline__ u16 f2bf(float f) {
  u32 u = __float_as_uint(f);
  return (u16)((u + 0x7fffu + ((u >> 16) & 1u)) >> 16);
}
__device__ __forceinline__ float bflo(u32 u) { return __uint_as_float(u << 16); }
__device__ __forceinline__ float bfhi(u32 u) { return __uint_as_float(u & 0xffff0000u); }
__device__ __forceinline__ float b2f(u16 v) { return __uint_as_float((u32)v << 16); }

// ---------------- prep: bf16 packs. wih transposed [dir][k][1024]; whh in MFMA B-fragment order ----------------
// wfrag[d][hh][w][ks][gate][lane][j]: n = gate*256 + hh*128 + w*16 + (lane&15); k = ks*32 + ((lane>>4)&3)*8 + j
__global__ void prep_kernel(const float* __restrict__ wih0, const float* __restrict__ whh0,
                            const float* __restrict__ bih0, const float* __restrict__ bhh0,
                            const float* __restrict__ wih1, const float* __restrict__ whh1,
                            const float* __restrict__ bih1, const float* __restrict__ bhh1,
                            u16* __restrict__ wih0t, u16* __restrict__ wih1t,
                            u16* __restrict__ wfrag0, u16* __restrict__ wfrag1,
                            float* __restrict__ bias0, float* __restrict__ bias1) {
  int tid = blockIdx.x * blockDim.x + threadIdx.x;
  int nth = gridDim.x * blockDim.x;
  for (int idx = tid; idx < 2 * 256 * 1024; idx += nth) {
    int d = idx >> 18, rem = idx & 262143, e = rem >> 10, r = rem & 1023;
    wih0t[idx] = f2bf(wih0[(d * 1024 + r) * 256 + e]);
  }
  for (int idx = tid; idx < 2 * 512 * 1024; idx += nth) {
    int d = idx >> 19, rem = idx & 524287, e = rem >> 10, r = rem & 1023;
    wih1t[idx] = f2bf(wih1[(d * 1024 + r) * 512 + e]);
  }
  for (int idx = tid; idx < 524288; idx += nth) {
    int j = idx & 7, lane = (idx >> 3) & 63, gate = (idx >> 9) & 3,
        ks = (idx >> 11) & 7, w = (idx >> 14) & 7, hh = (idx >> 17) & 1, d = (idx >> 18) & 1;
    int n = gate * 256 + hh * 128 + w * 16 + (lane & 15);
    int k = ks * 32 + ((lane >> 4) & 3) * 8 + j;
    wfrag0[idx] = f2bf(whh0[(d * 1024 + n) * 256 + k]);
    wfrag1[idx] = f2bf(whh1[(d * 1024 + n) * 256 + k]);
  }
  for (int idx = tid; idx < 2 * 1024; idx += nth) {
    bias0[idx] = bih0[idx] + bhh0[idx];
    bias1[idx] = bih1[idx] + bhh1[idx];
  }
}

// ---------------- input-projection GEMM: gx[dir][m][1024] = X[m] @ Wt[dir] + bias ----------------
template <int K, bool GATHER>
__global__ __launch_bounds__(256) void gemm_gx(
    const void* __restrict__ xsrc_v,
    const int* __restrict__ sent,
    const u16* __restrict__ wt,       // [2][K][1024] bf16
    const float* __restrict__ bias,   // [2][1024]
    u16* __restrict__ gx)             // [2*M][1024] bf16
{
  constexpr int BM = 64, BN = 64, BK = 32;
  __shared__ float Xs[BK][BM];
  __shared__ float Ws[BK][BN];
  const int tid = threadIdx.x;
  const int tx = tid & 15, ty = tid >> 4;
  const int n0 = blockIdx.x * BN;
  const int m0 = blockIdx.y * BM;
  const int dir = blockIdx.z;

  const int lrow = tid >> 3;
  const int lk = (tid & 7) * 4;
  const int wk = tid >> 3;
  const int wn = (tid & 7) * 8;

  float acc[4][4] = {};

  for (int k0 = 0; k0 < K; k0 += BK) {
#pragma unroll
    for (int rr = 0; rr < 2; ++rr) {
      int m = m0 + lrow + rr * 32;
      if constexpr (GATHER) {
        const float* xrow = (const float*)xsrc_v + (size_t)sent[m] * K;
        float4 v = *reinterpret_cast<const float4*>(xrow + k0 + lk);
        Xs[lk + 0][lrow + rr * 32] = v.x;
        Xs[lk + 1][lrow + rr * 32] = v.y;
        Xs[lk + 2][lrow + rr * 32] = v.z;
        Xs[lk + 3][lrow + rr * 32] = v.w;
      } else {
        const u16* xrow = (const u16*)xsrc_v + (size_t)m * K;
        uint2 v = *reinterpret_cast<const uint2*>(xrow + k0 + lk);
        Xs[lk + 0][lrow + rr * 32] = bflo(v.x);
        Xs[lk + 1][lrow + rr * 32] = bfhi(v.x);
        Xs[lk + 2][lrow + rr * 32] = bflo(v.y);
        Xs[lk + 3][lrow + rr * 32] = bfhi(v.y);
      }
    }
    {
      const u16* wp = wt + ((size_t)dir * K + k0 + wk) * 1024 + n0 + wn;
      uint4 wv = *reinterpret_cast<const uint4*>(wp);
      Ws[wk][wn + 0] = bflo(wv.x); Ws[wk][wn + 1] = bfhi(wv.x);
      Ws[wk][wn + 2] = bflo(wv.y); Ws[wk][wn + 3] = bfhi(wv.y);
      Ws[wk][wn + 4] = bflo(wv.z); Ws[wk][wn + 5] = bfhi(wv.z);
      Ws[wk][wn + 6] = bflo(wv.w); Ws[wk][wn + 7] = bfhi(wv.w);
    }
    __syncthreads();
#pragma unroll 8
    for (int k = 0; k < BK; ++k) {
      float4 a = *reinterpret_cast<const float4*>(&Xs[k][ty * 4]);
      float4 b = *reinterpret_cast<const float4*>(&Ws[k][tx * 4]);
      acc[0][0] += a.x * b.x; acc[0][1] += a.x * b.y; acc[0][2] += a.x * b.z; acc[0][3] += a.x * b.w;
      acc[1][0] += a.y * b.x; acc[1][1] += a.y * b.y; acc[1][2] += a.y * b.z; acc[1][3] += a.y * b.w;
      acc[2][0] += a.z * b.x; acc[2][1] += a.z * b.y; acc[2][2] += a.z * b.z; acc[2][3] += a.z * b.w;
      acc[3][0] += a.w * b.x; acc[3][1] += a.w * b.y; acc[3][2] += a.w * b.z; acc[3][3] += a.w * b.w;
    }
    __syncthreads();
  }

  float4 bv = *reinterpret_cast<const float4*>(&bias[dir * 1024 + n0 + tx * 4]);
#pragma unroll
  for (int i = 0; i < 4; ++i) {
    int m = m0 + ty * 4 + i;
    ushort4 sv;
    sv.x = f2bf(acc[i][0] + bv.x);
    sv.y = f2bf(acc[i][1] + bv.y);
    sv.z = f2bf(acc[i][2] + bv.z);
    sv.w = f2bf(acc[i][3] + bv.w);
    *reinterpret_cast<ushort4*>(gx + ((size_t)dir * Mn + m) * 1024 + n0 + tx * 4) = sv;
  }
}

// ---------------- MFMA recurrence v4: 16 WGs x 512 thr; weights in VGPRs; sentinel-in-data IC exchange ----------
// WG (g = bid&7, hh = bid>>3): group g = dir*4+bg (16 batches), computes units [hh*128,(hh+1)*128).
// Per step: h[16x256] @ Whh-half -> 16x512 gates (8 waves x 4 gate-tiles of its 16-unit slice).
// Own-half h -> Ah via LDS. Peer-half via hx[g][hh][s][512] u64 (per-step, 0xFF sentinel): the polling
// load IS the data load — one IC round trip per step. No flags, no producer barrier before publish.
__global__ __launch_bounds__(512, 2) void lstm_recur_mfma(
    const uint4* __restrict__ wfrag,  // [2][2][8][8][4][64] uint4
    const u16* __restrict__ gx,       // [2*Mn][1024] bf16
    u64* __restrict__ hx,             // [8][2][512][512] u64
    u16* __restrict__ out)            // [B][S][512] bf16
{
  __shared__ u16 Ah[16][264];         // h_{s-1}: [batch][unit]
  const int tid = threadIdx.x;
  const int l = tid & 63;
  const int w = tid >> 6;             // wave 0..7
  const int g = blockIdx.x & 7;
  const int hh = blockIdx.x >> 3;
  const int dir = g >> 2, bg = g & 3;
  const int m0 = ((l >> 4) & 3) * 4;  // batch sub-group (C-frag rows / reg r)
  const int ucol = w * 16 + (l & 15); // unit within this WG's half (update phase)
  const int u = hh * 128 + ucol;      // global unit within dir
  float c[4] = {0.f, 0.f, 0.f, 0.f};

  // B fragments: all 4 gates of this wave's 16-unit slice, 8 k-steps -> 128 VGPRs, loaded once
  uint4 Breg[8][4];
  {
    const uint4* wf = wfrag + (((size_t)(dir * 2 + hh) * 8 + w) * 2048);
#pragma unroll
    for (int ks = 0; ks < 8; ++ks)
#pragma unroll
      for (int gi = 0; gi < 4; ++gi)
        Breg[ks][gi] = wf[(ks * 4 + gi) * 64 + l];
  }

  const u64* peer = hx + (((size_t)g * 2 + (1 - hh)) * 512) * 512;
  u64* mine = hx + (((size_t)g * 2 + hh) * 512) * 512;
  const int pu = tid >> 2, pmg = tid & 3;  // peer-scatter assignment

  for (int s = 0; s < Sn; ++s) {
    const int t = dir ? (Sn - 1 - s) : s;

    // gx loads issued early; consumed in update phase
    u16 gxv[4][4];
#pragma unroll
    for (int r = 0; r < 4; ++r) {
      const u16* p = gx + ((size_t)(dir * Mn + (bg * 16 + m0 + r) * Sn + t)) * 1024 + u;
#pragma unroll
      for (int gi = 0; gi < 4; ++gi) gxv[gi][r] = p[gi * 256];
    }

    f32x4 acc[4];
#pragma unroll
    for (int gi = 0; gi < 4; ++gi) acc[gi] = (f32x4){0.f, 0.f, 0.f, 0.f};

    if (s > 0) {
      // poll peer half of h_{s-1}: the polling load IS the data load
      const u64* pp = peer + (size_t)(s - 1) * 512 + tid;
      u64 hv;
      do {
        hv = __hip_atomic_load(pp, __ATOMIC_RELAXED, __HIP_MEMORY_SCOPE_AGENT);
        if (hv != ~0ULL) break;
        __builtin_amdgcn_s_sleep(1);
      } while (true);
#pragma unroll
      for (int r = 0; r < 4; ++r)
        Ah[pmg * 4 + r][(1 - hh) * 128 + pu] = (u16)(hv >> (r * 16));
      __syncthreads();   // peer + own h_{s-1} all visible in Ah
#pragma unroll
      for (int ks = 0; ks < 8; ++ks) {
        uint4 av = *reinterpret_cast<const uint4*>(&Ah[l & 15][ks * 32 + ((l >> 4) & 3) * 8]);
        short8 a8 = __builtin_bit_cast(short8, av);
#pragma unroll
        for (int gi = 0; gi < 4; ++gi)
          acc[gi] = __builtin_amdgcn_mfma_f32_16x16x32_bf16(a8, __builtin_bit_cast(short8, Breg[ks][gi]), acc[gi], 0, 0, 0);
      }
      __syncthreads();   // MFMA done reading Ah before update overwrites own half
    }

    // lane-local LSTM update: 4 batches x 1 unit (unit ucol of this half)
    u16 hbf[4];
#pragma unroll
    for (int r = 0; r < 4; ++r) {
      float gi_ = acc[0][r] + b2f(gxv[0][r]);
      float gf_ = acc[1][r] + b2f(gxv[1][r]);
      float gg_ = acc[2][r] + b2f(gxv[2][r]);
      float go_ = acc[3][r] + b2f(gxv[3][r]);
      c[r] = sigf(gf_) * c[r] + sigf(gi_) * tanh_f(gg_);
      float h = sigf(go_) * tanh_f(c[r]);
      hbf[r] = f2bf(h);
      Ah[m0 + r][u] = hbf[r];   // own half, consumed next step after barrier
    }
    {
      u64 hpack = (u64)hbf[0] | ((u64)hbf[1] << 16) | ((u64)hbf[2] << 32) | ((u64)hbf[3] << 48);
      __hip_atomic_store(mine + (size_t)s * 512 + ucol * 4 + (m0 >> 2), hpack,
                         __ATOMIC_RELAXED, __HIP_MEMORY_SCOPE_AGENT);
    }
#pragma unroll
    for (int r = 0; r < 4; ++r)
      out[((size_t)(bg * 16 + m0 + r) * Sn + t) * HIDn + dir * Hn + u] = hbf[r];
  }
}

// ---------------- FC: one wave per (b,t), bf16 input rows ----------------
__global__ __launch_bounds__(64) void fc_kernel(const u16* __restrict__ out1,
                                                const float* __restrict__ fcw,
                                                const float* __restrict__ fcb,
                                                float* __restrict__ feats) {
  const int bs = blockIdx.x;
  const int l = threadIdx.x;
  const u16* row = out1 + (size_t)bs * HIDn;
  uint4 rv = *reinterpret_cast<const uint4*>(row + l * 8);
  float v[8];
  v[0] = bflo(rv.x); v[1] = bfhi(rv.x);
  v[2] = bflo(rv.y); v[3] = bfhi(rv.y);
  v[4] = bflo(rv.z); v[5] = bfhi(rv.z);
  v[6] = bflo(rv.w); v[7] = bfhi(rv.w);
#pragma unroll
  for (int tag = 0; tag < Tn; ++tag) {
    const float* w = fcw + tag * HIDn + l * 8;
    float4 w0 = *reinterpret_cast<const float4*>(w);
    float4 w1 = *reinterpret_cast<const float4*>(w + 4);
    float acc = v[0] * w0.x + v[1] * w0.y + v[2] * w0.z + v[3] * w0.w
              + v[4] * w1.x + v[5] * w1.y + v[6] * w1.z + v[7] * w1.w;
#pragma unroll
    for (int off = 32; off; off >>= 1) acc += __shfl_xor(acc, off);
    if (l == 0) feats[bs * Tn + tag] = acc + fcb[tag];
  }
}

// ---------------- CRF forward + gold, one wave per batch ----------------
__global__ __launch_bounds__(64) void crf_kernel(const float* __restrict__ feats,
                                                 const int* __restrict__ tags,
                                                 const int* __restrict__ lens,
                                                 const float* __restrict__ trans,
                                                 float* __restrict__ scores) {
  const int b = blockIdx.x;
  const int j = threadIdx.x;
  const int jj = j < Tn ? j : Tn - 1;
  const int len = lens[b];

  float trc[Tn];
#pragma unroll
  for (int i = 0; i < Tn; ++i) trc[i] = trans[i * Tn + jj];
  const float trS = trans[jj * Tn + STOP_T];

  float alpha = (j == START_T) ? 0.0f : NEGV;
  const float* fb = feats + (size_t)b * Sn * Tn;

  for (int t = 0; t < Sn; ++t) {
    float f = (j < Tn) ? fb[t * Tn + j] : 0.0f;
    float v[Tn];
    float m = -3.0e38f;
#pragma unroll
    for (int i = 0; i < Tn; ++i) {
      float ai = __shfl(alpha, i);
      v[i] = ai + trc[i];
      m = fmaxf(m, v[i]);
    }
    float ssum = 0.0f;
#pragma unroll
    for (int i = 0; i < Tn; ++i) ssum += __expf(v[i] - m);
    float newa = m + __logf(ssum) + f;
    if (t < len && j < Tn) alpha = newa;
  }

  float val = (j < Tn) ? alpha + trS : -3.0e38f;
  float m = val;
#pragma unroll
  for (int off = 32; off; off >>= 1) m = fmaxf(m, __shfl_xor(m, off));
  float se = (j < Tn) ? __expf(val - m) : 0.0f;
#pragma unroll
  for (int off = 32; off; off >>= 1) se += __shfl_xor(se, off);
  float fscore = m + __logf(se);

  const int* tg = tags + b * Sn;
  float part = 0.0f;
  for (int q = 0; q < 8; ++q) {
    int s0 = j * 8 + q;
    if (s0 < Sn - 1 && (s0 + 1) < len) {
      int ta = tg[s0], tb = tg[s0 + 1];
      part += trans[ta * Tn + tb] + fb[s0 * Tn + tb];
    }
  }
#pragma unroll
  for (int off = 32; off; off >>= 1) part += __shfl_xor(part, off);

  if (j == 0) {
    int t0 = tg[0];
    int tl = tg[len - 1];
    float gold = trans[START_T * Tn + t0] + fb[0 * Tn + t0] + part + trans[tl * Tn + STOP_T];
    scores[b] = fscore - gold;
  }
}

__global__ void finalize_kernel(const float* __restrict__ scores, float* __restrict__ out) {
  int l = threadIdx.x;
  float v = scores[l];
#pragma unroll
  for (int off = 32; off; off >>= 1) v += __shfl_xor(v, off);
  if (l == 0) out[0] = v / 64.0f;
}

extern "C" void kernel_launch(void* const* d_in, const int* in_sizes, int n_in,
                              void* d_out, int out_size, void* d_ws, size_t ws_size,
                              hipStream_t stream) {
  const int* sent = (const int*)d_in[0];
  const int* tags = (const int*)d_in[1];
  const int* lens = (const int*)d_in[2];
  const float* emb = (const float*)d_in[3];
  const float* wih0 = (const float*)d_in[4];
  const float* whh0 = (const float*)d_in[5];
  const float* bih0 = (const float*)d_in[6];
  const float* bhh0 = (const float*)d_in[7];
  const float* wih1 = (const float*)d_in[8];
  const float* whh1 = (const float*)d_in[9];
  const float* bih1 = (const float*)d_in[10];
  const float* bhh1 = (const float*)d_in[11];
  const float* fcw = (const float*)d_in[12];
  const float* fcb = (const float*)d_in[13];
  const float* trans = (const float*)d_in[14];

  // workspace (~208 MB): outb 33.5 + gx 134.2 (feats aliases) + hx 33.5 + weights ~6.3
  char* ws = (char*)d_ws;
  u16* outb = (u16*)ws;                                  // 33,554,432 B
  u16* gx = (u16*)(ws + 33554432);                       // 134,217,728 B
  float* feats = (float*)gx;                             // aliases gx (dead before fc)
  char* p = ws + 33554432 + 134217728;
  u64* hx = (u64*)p;                    p += 33554432;   // [8][2][512][512] u64 (shared by both layers)
  float* scores = (float*)p;            p += 256;
  float* bias0 = (float*)p;             p += 8192;
  float* bias1 = (float*)p;             p += 8192;
  u16* wih0t = (u16*)p;                 p += 1048576;
  u16* wih1t = (u16*)p;                 p += 2097152;
  u16* wfrag0 = (u16*)p;                p += 1048576;
  u16* wfrag1 = (u16*)p;                p += 1048576;

  prep_kernel<<<2048, 256, 0, stream>>>(wih0, whh0, bih0, bhh0, wih1, whh1, bih1, bhh1,
                                        wih0t, wih1t, wfrag0, wfrag1, bias0, bias1);

  dim3 ggrid(1024 / 64, Mn / 64, 2);
  hipMemsetAsync(hx, 0xFF, 33554432, stream);            // sentinel for layer-0 exchange
  gemm_gx<256, true><<<ggrid, 256, 0, stream>>>(emb, sent, wih0t, bias0, gx);
  lstm_recur_mfma<<<16, 512, 0, stream>>>((const uint4*)wfrag0, gx, hx, outb);
  hipMemsetAsync(hx, 0xFF, 33554432, stream);            // re-sentinel for layer-1
  gemm_gx<512, false><<<ggrid, 256, 0, stream>>>(outb, nullptr, wih1t, bias1, gx);
  lstm_recur_mfma<<<16, 512, 0, stream>>>((const uint4*)wfrag1, gx, hx, outb);

  fc_kernel<<<Mn, 64, 0, stream>>>(outb, fcw, fcb, feats);
  crf_kernel<<<Bn, 64, 0, stream>>>(feats, tags, lens, trans, scores);
  finalize_kernel<<<1, 64, 0, stream>>>(scores, (float*)d_out);
}

// Round 10
// 4264.595 us; speedup vs baseline: 1.6422x; 1.0049x over previous
//
#include <hip/hip_runtime.h>
#include <math.h>

#define NEGV (-100000.0f)
constexpr int Bn = 64, Sn = 512, En = 256, Hn = 256, HIDn = 512, Tn = 9;
constexpr int START_T = Tn - 2, STOP_T = Tn - 1;
constexpr int Mn = Bn * Sn; // 32768 rows

typedef unsigned int u32;
typedef unsigned short u16;
typedef unsigned long long u64;
typedef short short8 __attribute__((ext_vector_type(8)));
typedef float f32x4 __attribute__((ext_vector_type(4)));

__device__ __forceinline__ float sigf(float x) { return 1.0f / (1.0f + __expf(-x)); }
__device__ __forceinline__ float tanh_f(float x) { return 2.0f / (1.0f + __expf(-2.0f * x)) - 1.0f; }
__device__ __forceinline__ u16 f2bf(float f) {
  u32 u = __float_as_uint(f);
  return (u16)((u + 0x7fffu + ((u >> 16) & 1u)) >> 16);
}
__device__ __forceinline__ float bflo(u32 u) { return __uint_as_float(u << 16); }
__device__ __forceinline__ float bfhi(u32 u) { return __uint_as_float(u & 0xffff0000u); }
__device__ __forceinline__ float b2f(u16 v) { return __uint_as_float((u32)v << 16); }

// ---------------- prep: bf16 packs. wih transposed [dir][k][1024]; whh in B-frag order per (dir,quarter) ------
// wfrag[d][nq][ks][tau][lane][j]; tau = ub*4 + gate; unit = nq*64 + ub*16 + (lane&15);
// whh row = gate*256 + unit; k = ks*32 + ((lane>>4)&3)*8 + j
__global__ void prep_kernel(const float* __restrict__ wih0, const float* __restrict__ whh0,
                            const float* __restrict__ bih0, const float* __restrict__ bhh0,
                            const float* __restrict__ wih1, const float* __restrict__ whh1,
                            const float* __restrict__ bih1, const float* __restrict__ bhh1,
                            u16* __restrict__ wih0t, u16* __restrict__ wih1t,
                            u16* __restrict__ wfrag0, u16* __restrict__ wfrag1,
                            float* __restrict__ bias0, float* __restrict__ bias1) {
  int tid = blockIdx.x * blockDim.x + threadIdx.x;
  int nth = gridDim.x * blockDim.x;
  for (int idx = tid; idx < 2 * 256 * 1024; idx += nth) {
    int d = idx >> 18, rem = idx & 262143, e = rem >> 10, r = rem & 1023;
    wih0t[idx] = f2bf(wih0[(d * 1024 + r) * 256 + e]);
  }
  for (int idx = tid; idx < 2 * 512 * 1024; idx += nth) {
    int d = idx >> 19, rem = idx & 524287, e = rem >> 10, r = rem & 1023;
    wih1t[idx] = f2bf(wih1[(d * 1024 + r) * 512 + e]);
  }
  for (int idx = tid; idx < 524288; idx += nth) {
    int j = idx & 7, lane = (idx >> 3) & 63, tau = (idx >> 9) & 15,
        ks = (idx >> 13) & 7, nq = (idx >> 16) & 3, d = (idx >> 18) & 1;
    int ub = tau >> 2, gate = tau & 3;
    int unit = nq * 64 + ub * 16 + (lane & 15);
    int row = gate * 256 + unit;
    int k = ks * 32 + ((lane >> 4) & 3) * 8 + j;
    wfrag0[idx] = f2bf(whh0[(d * 1024 + row) * 256 + k]);
    wfrag1[idx] = f2bf(whh1[(d * 1024 + row) * 256 + k]);
  }
  for (int idx = tid; idx < 2 * 1024; idx += nth) {
    bias0[idx] = bih0[idx] + bhh0[idx];
    bias1[idx] = bih1[idx] + bhh1[idx];
  }
}

// ---------------- input-projection GEMM -> gate-packed gx2[dir][m][unit][gate] ----------------
template <int K, bool GATHER>
__global__ __launch_bounds__(256) void gemm_gx(
    const void* __restrict__ xsrc_v,
    const int* __restrict__ sent,
    const u16* __restrict__ wt,       // [2][K][1024] bf16
    const float* __restrict__ bias,   // [2][1024]
    u16* __restrict__ gx2)            // [2*M][256][4] bf16
{
  constexpr int BM = 64, BN = 64, BK = 32;
  __shared__ float Xs[BK][BM];
  __shared__ float Ws[BK][BN];
  const int tid = threadIdx.x;
  const int tx = tid & 15, ty = tid >> 4;
  const int n0 = blockIdx.x * BN;
  const int m0 = blockIdx.y * BM;
  const int dir = blockIdx.z;

  const int lrow = tid >> 3;
  const int lk = (tid & 7) * 4;
  const int wk = tid >> 3;
  const int wn = (tid & 7) * 8;

  float acc[4][4] = {};

  for (int k0 = 0; k0 < K; k0 += BK) {
#pragma unroll
    for (int rr = 0; rr < 2; ++rr) {
      int m = m0 + lrow + rr * 32;
      if constexpr (GATHER) {
        const float* xrow = (const float*)xsrc_v + (size_t)sent[m] * K;
        float4 v = *reinterpret_cast<const float4*>(xrow + k0 + lk);
        Xs[lk + 0][lrow + rr * 32] = v.x;
        Xs[lk + 1][lrow + rr * 32] = v.y;
        Xs[lk + 2][lrow + rr * 32] = v.z;
        Xs[lk + 3][lrow + rr * 32] = v.w;
      } else {
        const u16* xrow = (const u16*)xsrc_v + (size_t)m * K;
        uint2 v = *reinterpret_cast<const uint2*>(xrow + k0 + lk);
        Xs[lk + 0][lrow + rr * 32] = bflo(v.x);
        Xs[lk + 1][lrow + rr * 32] = bfhi(v.x);
        Xs[lk + 2][lrow + rr * 32] = bflo(v.y);
        Xs[lk + 3][lrow + rr * 32] = bfhi(v.y);
      }
    }
    {
      const u16* wp = wt + ((size_t)dir * K + k0 + wk) * 1024 + n0 + wn;
      uint4 wv = *reinterpret_cast<const uint4*>(wp);
      Ws[wk][wn + 0] = bflo(wv.x); Ws[wk][wn + 1] = bfhi(wv.x);
      Ws[wk][wn + 2] = bflo(wv.y); Ws[wk][wn + 3] = bfhi(wv.y);
      Ws[wk][wn + 4] = bflo(wv.z); Ws[wk][wn + 5] = bfhi(wv.z);
      Ws[wk][wn + 6] = bflo(wv.w); Ws[wk][wn + 7] = bfhi(wv.w);
    }
    __syncthreads();
#pragma unroll 8
    for (int k = 0; k < BK; ++k) {
      float4 a = *reinterpret_cast<const float4*>(&Xs[k][ty * 4]);
      float4 b = *reinterpret_cast<const float4*>(&Ws[k][tx * 4]);
      acc[0][0] += a.x * b.x; acc[0][1] += a.x * b.y; acc[0][2] += a.x * b.z; acc[0][3] += a.x * b.w;
      acc[1][0] += a.y * b.x; acc[1][1] += a.y * b.y; acc[1][2] += a.y * b.z; acc[1][3] += a.y * b.w;
      acc[2][0] += a.z * b.x; acc[2][1] += a.z * b.y; acc[2][2] += a.z * b.z; acc[2][3] += a.z * b.w;
      acc[3][0] += a.w * b.x; acc[3][1] += a.w * b.y; acc[3][2] += a.w * b.z; acc[3][3] += a.w * b.w;
    }
    __syncthreads();
  }

  float4 bv = *reinterpret_cast<const float4*>(&bias[dir * 1024 + n0 + tx * 4]);
  const int nbase = n0 + tx * 4;      // 4 consecutive n: same gate, consecutive units
  const int gate = nbase >> 8;
  const int unit = nbase & 255;
#pragma unroll
  for (int i = 0; i < 4; ++i) {
    int m = m0 + ty * 4 + i;
    u16* dst = gx2 + ((size_t)(dir * Mn + m) * 256 + unit) * 4 + gate;
    dst[0]  = f2bf(acc[i][0] + bv.x);
    dst[4]  = f2bf(acc[i][1] + bv.y);
    dst[8]  = f2bf(acc[i][2] + bv.z);
    dst[12] = f2bf(acc[i][3] + bv.w);
  }
}

// ---------------- MFMA recurrence v5: 32 WGs x 512; B in LDS; K-split; sentinel-in-data exchange --------------
// WG (g = bid&7 = dir*4+bg, nq = bid>>3): 16 batches x units [nq*64,(nq+1)*64).
// Waves: ub = w&3 (unit block), kh = w>>2 (K half, ks in [kh*4, kh*4+4)). Partials reduced via LDS.
// h exchange: hx[g][q][s][256] u64, 0xFF sentinel -> polling load IS the data load (one IC hop/step).
__global__ __launch_bounds__(512, 2) void lstm_recur_mfma(
    const uint4* __restrict__ wfrag,  // [2][4][2048] uint4
    const u16* __restrict__ gx2,      // [2*Mn][256][4] bf16
    u64* __restrict__ hx,             // [8][4][512][256] u64
    u16* __restrict__ out)            // [B][S][512] bf16
{
  __shared__ uint4 Bs[8192];          // 128 KB: [ks][tau][lane]
  __shared__ u16 Ah[16][264];         // h_{s-1}: [batch][unit 0..255]
  __shared__ f32x4 Pt[16][64];        // 16 KB: K-half-1 partials [tau][lane]
  const int tid = threadIdx.x;
  const int l = tid & 63;
  const int w = tid >> 6;
  const int kh = w >> 2;
  const int ub = w & 3;
  const int g = blockIdx.x & 7;
  const int nq = blockIdx.x >> 3;
  const int dir = g >> 2, bg = g & 3;
  const int quad = (l >> 4) & 3;
  const int m0 = quad * 4;
  const int col = l & 15;
  const int uq = ub * 16 + col;       // unit within quarter (kh0 update role)
  const int u = nq * 64 + uq;         // unit within dir

  // stage the B quarter into LDS once
  {
    const uint4* wf = wfrag + ((size_t)(dir * 4 + nq)) * 2048;
#pragma unroll
    for (int i = 0; i < 16; ++i) Bs[tid + i * 512] = wf[tid + i * 512];
  }
  u64* mine = hx + ((size_t)(g * 4 + nq) * 512) * 256;
  float c[4] = {0.f, 0.f, 0.f, 0.f};
  __syncthreads();

  for (int s = 0; s < Sn; ++s) {
    const int t = dir ? (Sn - 1 - s) : s;

    // gate-packed gx loads (kh0 lanes only): 4 x dwordx2
    uint2 gxv[4];
    if (kh == 0) {
#pragma unroll
      for (int r = 0; r < 4; ++r)
        gxv[r] = *reinterpret_cast<const uint2*>(
            gx2 + ((size_t)(dir * Mn + (bg * 16 + m0 + r) * Sn + t) * 256 + u) * 4);
    }

    f32x4 acc[4];
#pragma unroll
    for (int gi = 0; gi < 4; ++gi) acc[gi] = (f32x4){0.f, 0.f, 0.f, 0.f};

    if (s > 0) {
      // gather 3 peer quarters of h_{s-1}: 768 u64 over 512 threads; polling load IS the data load
#pragma unroll
      for (int pass = 0; pass < 2; ++pass) {
        int idx = tid + pass * 512;
        if (idx < 768) {
          int pq = idx >> 8, off = idx & 255;
          int pqr = pq + (pq >= nq ? 1 : 0);
          const u64* pp = hx + ((size_t)(g * 4 + pqr) * 512 + (s - 1)) * 256 + off;
          u64 hv;
          do {
            hv = __hip_atomic_load(pp, __ATOMIC_RELAXED, __HIP_MEMORY_SCOPE_AGENT);
            if (hv != ~0ULL) break;
            __builtin_amdgcn_s_sleep(1);
          } while (true);
          int unit = off >> 2, mg = off & 3;
#pragma unroll
          for (int r = 0; r < 4; ++r)
            Ah[mg * 4 + r][pqr * 64 + unit] = (u16)(hv >> (r * 16));
        }
      }
    }
    __syncthreads();   // Ah (peer quarters + own from update phase) complete

    if (s > 0) {
#pragma unroll
      for (int ks2 = 0; ks2 < 4; ++ks2) {
        int ks = kh * 4 + ks2;
        uint4 av = *reinterpret_cast<const uint4*>(&Ah[col][ks * 32 + quad * 8]);
        short8 a8 = __builtin_bit_cast(short8, av);
#pragma unroll
        for (int gi = 0; gi < 4; ++gi)
          acc[gi] = __builtin_amdgcn_mfma_f32_16x16x32_bf16(
              a8, __builtin_bit_cast(short8, Bs[(ks * 16 + ub * 4 + gi) * 64 + l]), acc[gi], 0, 0, 0);
      }
      if (kh == 1)
#pragma unroll
        for (int gi = 0; gi < 4; ++gi) Pt[ub * 4 + gi][l] = acc[gi];
    }
    __syncthreads();   // partials visible; all Ah reads complete

    if (kh == 0) {
      if (s > 0)
#pragma unroll
        for (int gi = 0; gi < 4; ++gi) acc[gi] += Pt[ub * 4 + gi][l];
      u16 hbf[4];
#pragma unroll
      for (int r = 0; r < 4; ++r) {
        float gi_ = acc[0][r] + b2f((u16)(gxv[r].x & 0xffff));
        float gf_ = acc[1][r] + b2f((u16)(gxv[r].x >> 16));
        float gg_ = acc[2][r] + b2f((u16)(gxv[r].y & 0xffff));
        float go_ = acc[3][r] + b2f((u16)(gxv[r].y >> 16));
        c[r] = sigf(gf_) * c[r] + sigf(gi_) * tanh_f(gg_);
        float h = sigf(go_) * tanh_f(c[r]);
        hbf[r] = f2bf(h);
        Ah[m0 + r][u] = hbf[r];     // own column, consumed next step after barrier
        out[((size_t)(bg * 16 + m0 + r) * Sn + t) * HIDn + dir * Hn + u] = hbf[r];
      }
      u64 hpack = (u64)hbf[0] | ((u64)hbf[1] << 16) | ((u64)hbf[2] << 32) | ((u64)hbf[3] << 48);
      __hip_atomic_store(mine + (size_t)s * 256 + uq * 4 + quad, hpack,
                         __ATOMIC_RELAXED, __HIP_MEMORY_SCOPE_AGENT);
    }
  }
}

// ---------------- FC: one wave per (b,t), bf16 input rows ----------------
__global__ __launch_bounds__(64) void fc_kernel(const u16* __restrict__ out1,
                                                const float* __restrict__ fcw,
                                                const float* __restrict__ fcb,
                                                float* __restrict__ feats) {
  const int bs = blockIdx.x;
  const int l = threadIdx.x;
  const u16* row = out1 + (size_t)bs * HIDn;
  uint4 rv = *reinterpret_cast<const uint4*>(row + l * 8);
  float v[8];
  v[0] = bflo(rv.x); v[1] = bfhi(rv.x);
  v[2] = bflo(rv.y); v[3] = bfhi(rv.y);
  v[4] = bflo(rv.z); v[5] = bfhi(rv.z);
  v[6] = bflo(rv.w); v[7] = bfhi(rv.w);
#pragma unroll
  for (int tag = 0; tag < Tn; ++tag) {
    const float* w = fcw + tag * HIDn + l * 8;
    float4 w0 = *reinterpret_cast<const float4*>(w);
    float4 w1 = *reinterpret_cast<const float4*>(w + 4);
    float acc = v[0] * w0.x + v[1] * w0.y + v[2] * w0.z + v[3] * w0.w
              + v[4] * w1.x + v[5] * w1.y + v[6] * w1.z + v[7] * w1.w;
#pragma unroll
    for (int off = 32; off; off >>= 1) acc += __shfl_xor(acc, off);
    if (l == 0) feats[bs * Tn + tag] = acc + fcb[tag];
  }
}

// ---------------- CRF forward + gold, one wave per batch ----------------
__global__ __launch_bounds__(64) void crf_kernel(const float* __restrict__ feats,
                                                 const int* __restrict__ tags,
                                                 const int* __restrict__ lens,
                                                 const float* __restrict__ trans,
                                                 float* __restrict__ scores) {
  const int b = blockIdx.x;
  const int j = threadIdx.x;
  const int jj = j < Tn ? j : Tn - 1;
  const int len = lens[b];

  float trc[Tn];
#pragma unroll
  for (int i = 0; i < Tn; ++i) trc[i] = trans[i * Tn + jj];
  const float trS = trans[jj * Tn + STOP_T];

  float alpha = (j == START_T) ? 0.0f : NEGV;
  const float* fb = feats + (size_t)b * Sn * Tn;

  for (int t = 0; t < Sn; ++t) {
    float f = (j < Tn) ? fb[t * Tn + j] : 0.0f;
    float v[Tn];
    float m = -3.0e38f;
#pragma unroll
    for (int i = 0; i < Tn; ++i) {
      float ai = __shfl(alpha, i);
      v[i] = ai + trc[i];
      m = fmaxf(m, v[i]);
    }
    float ssum = 0.0f;
#pragma unroll
    for (int i = 0; i < Tn; ++i) ssum += __expf(v[i] - m);
    float newa = m + __logf(ssum) + f;
    if (t < len && j < Tn) alpha = newa;
  }

  float val = (j < Tn) ? alpha + trS : -3.0e38f;
  float m = val;
#pragma unroll
  for (int off = 32; off; off >>= 1) m = fmaxf(m, __shfl_xor(m, off));
  float se = (j < Tn) ? __expf(val - m) : 0.0f;
#pragma unroll
  for (int off = 32; off; off >>= 1) se += __shfl_xor(se, off);
  float fscore = m + __logf(se);

  const int* tg = tags + b * Sn;
  float part = 0.0f;
  for (int q = 0; q < 8; ++q) {
    int s0 = j * 8 + q;
    if (s0 < Sn - 1 && (s0 + 1) < len) {
      int ta = tg[s0], tb = tg[s0 + 1];
      part += trans[ta * Tn + tb] + fb[s0 * Tn + tb];
    }
  }
#pragma unroll
  for (int off = 32; off; off >>= 1) part += __shfl_xor(part, off);

  if (j == 0) {
    int t0 = tg[0];
    int tl = tg[len - 1];
    float gold = trans[START_T * Tn + t0] + fb[0 * Tn + t0] + part + trans[tl * Tn + STOP_T];
    scores[b] = fscore - gold;
  }
}

__global__ void finalize_kernel(const float* __restrict__ scores, float* __restrict__ out) {
  int l = threadIdx.x;
  float v = scores[l];
#pragma unroll
  for (int off = 32; off; off >>= 1) v += __shfl_xor(v, off);
  if (l == 0) out[0] = v / 64.0f;
}

extern "C" void kernel_launch(void* const* d_in, const int* in_sizes, int n_in,
                              void* d_out, int out_size, void* d_ws, size_t ws_size,
                              hipStream_t stream) {
  const int* sent = (const int*)d_in[0];
  const int* tags = (const int*)d_in[1];
  const int* lens = (const int*)d_in[2];
  const float* emb = (const float*)d_in[3];
  const float* wih0 = (const float*)d_in[4];
  const float* whh0 = (const float*)d_in[5];
  const float* bih0 = (const float*)d_in[6];
  const float* bhh0 = (const float*)d_in[7];
  const float* wih1 = (const float*)d_in[8];
  const float* whh1 = (const float*)d_in[9];
  const float* bih1 = (const float*)d_in[10];
  const float* bhh1 = (const float*)d_in[11];
  const float* fcw = (const float*)d_in[12];
  const float* fcb = (const float*)d_in[13];
  const float* trans = (const float*)d_in[14];

  // workspace (~207 MB): outb 33.5 + gx2 134.2 (feats aliases) + hx 33.5 + weights ~6.3
  char* ws = (char*)d_ws;
  u16* outb = (u16*)ws;                                  // 33,554,432 B
  u16* gx2 = (u16*)(ws + 33554432);                      // 134,217,728 B
  float* feats = (float*)gx2;                            // aliases gx2 (dead before fc)
  char* p = ws + 33554432 + 134217728;
  u64* hx = (u64*)p;                    p += 33554432;   // [8][4][512][256] u64 (shared by layers)
  float* scores = (float*)p;            p += 256;
  float* bias0 = (float*)p;             p += 8192;
  float* bias1 = (float*)p;             p += 8192;
  u16* wih0t = (u16*)p;                 p += 1048576;
  u16* wih1t = (u16*)p;                 p += 2097152;
  u16* wfrag0 = (u16*)p;                p += 1048576;
  u16* wfrag1 = (u16*)p;                p += 1048576;

  prep_kernel<<<2048, 256, 0, stream>>>(wih0, whh0, bih0, bhh0, wih1, whh1, bih1, bhh1,
                                        wih0t, wih1t, wfrag0, wfrag1, bias0, bias1);

  dim3 ggrid(1024 / 64, Mn / 64, 2);
  hipMemsetAsync(hx, 0xFF, 33554432, stream);            // sentinel for layer-0 exchange
  gemm_gx<256, true><<<ggrid, 256, 0, stream>>>(emb, sent, wih0t, bias0, gx2);
  lstm_recur_mfma<<<32, 512, 0, stream>>>((const uint4*)wfrag0, gx2, hx, outb);
  hipMemsetAsync(hx, 0xFF, 33554432, stream);            // re-sentinel for layer-1
  gemm_gx<512, false><<<ggrid, 256, 0, stream>>>(outb, nullptr, wih1t, bias1, gx2);
  lstm_recur_mfma<<<32, 512, 0, stream>>>((const uint4*)wfrag1, gx2, hx, outb);

  fc_kernel<<<Mn, 64, 0, stream>>>(outb, fcw, fcb, feats);
  crf_kernel<<<Bn, 64, 0, stream>>>(feats, tags, lens, trans, scores);
  finalize_kernel<<<1, 64, 0, stream>>>(scores, (float*)d_out);
}

// Round 11
// 3226.789 us; speedup vs baseline: 2.1704x; 1.3216x over previous
//
#include <hip/hip_runtime.h>
#include <math.h>

#define NEGV (-100000.0f)
constexpr int Bn = 64, Sn = 512, En = 256, Hn = 256, HIDn = 512, Tn = 9;
constexpr int START_T = Tn - 2, STOP_T = Tn - 1;
constexpr int Mn = Bn * Sn; // 32768 rows

typedef unsigned int u32;
typedef unsigned short u16;
typedef unsigned long long u64;
typedef short short8 __attribute__((ext_vector_type(8)));
typedef float f32x4 __attribute__((ext_vector_type(4)));

__device__ __forceinline__ float sigf(float x) { return 1.0f / (1.0f + __expf(-x)); }
__device__ __forceinline__ float tanh_f(float x) { return 2.0f / (1.0f + __expf(-2.0f * x)) - 1.0f; }
__device__ __forceinline__ u16 f2bf(float f) {
  u32 u = __float_as_uint(f);
  return (u16)((u + 0x7fffu + ((u >> 16) & 1u)) >> 16);
}
__device__ __forceinline__ float bflo(u32 u) { return __uint_as_float(u << 16); }
__device__ __forceinline__ float bfhi(u32 u) { return __uint_as_float(u & 0xffff0000u); }
__device__ __forceinline__ float b2f(u16 v) { return __uint_as_float((u32)v << 16); }

// ---------------- prep: all weights to bf16 MFMA B-fragment order ----------------
// whh frags (recur):  wfrag[d][nq][ks][tau][lane][j]; tau=ub*4+gate; unit=nq*64+ub*16+(lane&15);
//                     row=gate*256+unit; k=ks*32+((lane>>4)&3)*8+j
// wih frags (gemm):   wifrag[d][nb][w][ks][lane][j]; n=nb*64+w*16+(lane&15); k=ks*32+((lane>>4)&3)*8+j
__global__ void prep_kernel(const float* __restrict__ wih0, const float* __restrict__ whh0,
                            const float* __restrict__ bih0, const float* __restrict__ bhh0,
                            const float* __restrict__ wih1, const float* __restrict__ whh1,
                            const float* __restrict__ bih1, const float* __restrict__ bhh1,
                            u16* __restrict__ wifrag0, u16* __restrict__ wifrag1,
                            u16* __restrict__ wfrag0, u16* __restrict__ wfrag1,
                            float* __restrict__ bias0, float* __restrict__ bias1) {
  int tid = blockIdx.x * blockDim.x + threadIdx.x;
  int nth = gridDim.x * blockDim.x;
  // wih0 frags: K=256, KS=8 -> 2*16*4*8*64*8 = 524288 u16
  for (int idx = tid; idx < 524288; idx += nth) {
    int j = idx & 7, lane = (idx >> 3) & 63, ks = (idx >> 9) & 7,
        w2 = (idx >> 12) & 3, nb = (idx >> 14) & 15, d = (idx >> 18) & 1;
    int n = nb * 64 + w2 * 16 + (lane & 15);
    int k = ks * 32 + ((lane >> 4) & 3) * 8 + j;
    wifrag0[idx] = f2bf(wih0[(d * 1024 + n) * 256 + k]);
  }
  // wih1 frags: K=512, KS=16 -> 2*16*4*16*64*8 = 1048576 u16
  for (int idx = tid; idx < 1048576; idx += nth) {
    int j = idx & 7, lane = (idx >> 3) & 63, ks = (idx >> 9) & 15,
        w2 = (idx >> 13) & 3, nb = (idx >> 15) & 15, d = (idx >> 19) & 1;
    int n = nb * 64 + w2 * 16 + (lane & 15);
    int k = ks * 32 + ((lane >> 4) & 3) * 8 + j;
    wifrag1[idx] = f2bf(wih1[(d * 1024 + n) * 512 + k]);
  }
  // whh frags (unchanged layout from round 10)
  for (int idx = tid; idx < 524288; idx += nth) {
    int j = idx & 7, lane = (idx >> 3) & 63, tau = (idx >> 9) & 15,
        ks = (idx >> 13) & 7, nq = (idx >> 16) & 3, d = (idx >> 18) & 1;
    int ub = tau >> 2, gate = tau & 3;
    int unit = nq * 64 + ub * 16 + (lane & 15);
    int row = gate * 256 + unit;
    int k = ks * 32 + ((lane >> 4) & 3) * 8 + j;
    wfrag0[idx] = f2bf(whh0[(d * 1024 + row) * 256 + k]);
    wfrag1[idx] = f2bf(whh1[(d * 1024 + row) * 256 + k]);
  }
  for (int idx = tid; idx < 2 * 1024; idx += nth) {
    bias0[idx] = bih0[idx] + bhh0[idx];
    bias1[idx] = bih1[idx] + bhh1[idx];
  }
}

// ---------------- MFMA input-projection GEMM -> gate-packed gx2[dir][m][unit][gate] ----------------
// Block: 256 thr, grid (Mn/64, 2). A (64 x K bf16) staged in LDS once; 16 n-tiles, no inner barriers.
template <int KS, bool GATHER>   // KS = K/32
__global__ __launch_bounds__(256) void gemm_ih(
    const void* __restrict__ xsrc_v,   // GATHER: fp32 emb; else bf16 rows [M][512]
    const int* __restrict__ sent,
    const uint4* __restrict__ wifrag,  // [2][16][4][KS][64] uint4
    const float* __restrict__ bias,    // [2][1024]
    u16* __restrict__ gx2)             // [2*M][256][4] bf16
{
  constexpr int K = KS * 32;
  constexpr int PITCH = K + 8;        // u16; K=256->264 (528B, 16B-mult), K=512->520 (1040B, 16B-mult)
  __shared__ u16 As[64][PITCH];
  const int tid = threadIdx.x;
  const int l = tid & 63;
  const int w = tid >> 6;
  const int col = l & 15;
  const int quad = (l >> 4) & 3;
  const int m0 = blockIdx.x * 64;
  const int dir = blockIdx.y;

  // stage A: row lr = tid>>2, quarter lq = tid&3
  {
    const int lr = tid >> 2, lq = tid & 3;
    if constexpr (GATHER) {
      const float4* xrow = reinterpret_cast<const float4*>(
          (const float*)xsrc_v + (size_t)sent[m0 + lr] * 256) + lq * 16;
      u32* dst = reinterpret_cast<u32*>(&As[lr][lq * 64]);
#pragma unroll
      for (int i = 0; i < 16; ++i) {
        float4 v = xrow[i];
        dst[i * 2 + 0] = (u32)f2bf(v.x) | ((u32)f2bf(v.y) << 16);
        dst[i * 2 + 1] = (u32)f2bf(v.z) | ((u32)f2bf(v.w) << 16);
      }
    } else {
      const uint4* xrow = reinterpret_cast<const uint4*>(
          (const u16*)xsrc_v + (size_t)(m0 + lr) * 512) + lq * 16;
      uint4* dst = reinterpret_cast<uint4*>(&As[lr][lq * 128]);
#pragma unroll
      for (int i = 0; i < 16; ++i) dst[i] = xrow[i];
    }
  }
  __syncthreads();

  const uint4* wfd = wifrag + (size_t)dir * 16 * 4 * KS * 64;
#pragma unroll 1
  for (int nb = 0; nb < 16; ++nb) {
    uint4 bf[KS];
#pragma unroll
    for (int ks = 0; ks < KS; ++ks)
      bf[ks] = wfd[((nb * 4 + w) * KS + ks) * 64 + l];

    f32x4 acc[4];
#pragma unroll
    for (int mt = 0; mt < 4; ++mt) acc[mt] = (f32x4){0.f, 0.f, 0.f, 0.f};
#pragma unroll
    for (int ks = 0; ks < KS; ++ks) {
      short8 b8 = __builtin_bit_cast(short8, bf[ks]);
#pragma unroll
      for (int mt = 0; mt < 4; ++mt) {
        uint4 av = *reinterpret_cast<const uint4*>(&As[mt * 16 + col][ks * 32 + quad * 8]);
        acc[mt] = __builtin_amdgcn_mfma_f32_16x16x32_bf16(
            __builtin_bit_cast(short8, av), b8, acc[mt], 0, 0, 0);
      }
    }

    const int n = nb * 64 + w * 16 + col;
    const int gate = n >> 8, unit = n & 255;
    const float bv = bias[dir * 1024 + n];
#pragma unroll
    for (int mt = 0; mt < 4; ++mt) {
#pragma unroll
      for (int r = 0; r < 4; ++r) {
        int m = m0 + mt * 16 + quad * 4 + r;
        gx2[((size_t)(dir * Mn + m) * 256 + unit) * 4 + gate] = f2bf(acc[mt][r] + bv);
      }
    }
  }
}

// ---------------- MFMA recurrence v5 (unchanged from round 10) --------------
__global__ __launch_bounds__(512, 2) void lstm_recur_mfma(
    const uint4* __restrict__ wfrag,  // [2][4][2048] uint4
    const u16* __restrict__ gx2,      // [2*Mn][256][4] bf16
    u64* __restrict__ hx,             // [8][4][512][256] u64
    u16* __restrict__ out)            // [B][S][512] bf16
{
  __shared__ uint4 Bs[8192];          // 128 KB: [ks][tau][lane]
  __shared__ u16 Ah[16][264];
  __shared__ f32x4 Pt[16][64];
  const int tid = threadIdx.x;
  const int l = tid & 63;
  const int w = tid >> 6;
  const int kh = w >> 2;
  const int ub = w & 3;
  const int g = blockIdx.x & 7;
  const int nq = blockIdx.x >> 3;
  const int dir = g >> 2, bg = g & 3;
  const int quad = (l >> 4) & 3;
  const int m0 = quad * 4;
  const int col = l & 15;
  const int uq = ub * 16 + col;
  const int u = nq * 64 + uq;

  {
    const uint4* wf = wfrag + ((size_t)(dir * 4 + nq)) * 2048;
#pragma unroll
    for (int i = 0; i < 16; ++i) Bs[tid + i * 512] = wf[tid + i * 512];
  }
  u64* mine = hx + ((size_t)(g * 4 + nq) * 512) * 256;
  float c[4] = {0.f, 0.f, 0.f, 0.f};
  __syncthreads();

  for (int s = 0; s < Sn; ++s) {
    const int t = dir ? (Sn - 1 - s) : s;

    uint2 gxv[4];
    if (kh == 0) {
#pragma unroll
      for (int r = 0; r < 4; ++r)
        gxv[r] = *reinterpret_cast<const uint2*>(
            gx2 + ((size_t)(dir * Mn + (bg * 16 + m0 + r) * Sn + t) * 256 + u) * 4);
    }

    f32x4 acc[4];
#pragma unroll
    for (int gi = 0; gi < 4; ++gi) acc[gi] = (f32x4){0.f, 0.f, 0.f, 0.f};

    if (s > 0) {
#pragma unroll
      for (int pass = 0; pass < 2; ++pass) {
        int idx = tid + pass * 512;
        if (idx < 768) {
          int pq = idx >> 8, off = idx & 255;
          int pqr = pq + (pq >= nq ? 1 : 0);
          const u64* pp = hx + ((size_t)(g * 4 + pqr) * 512 + (s - 1)) * 256 + off;
          u64 hv;
          do {
            hv = __hip_atomic_load(pp, __ATOMIC_RELAXED, __HIP_MEMORY_SCOPE_AGENT);
            if (hv != ~0ULL) break;
            __builtin_amdgcn_s_sleep(1);
          } while (true);
          int unit = off >> 2, mg = off & 3;
#pragma unroll
          for (int r = 0; r < 4; ++r)
            Ah[mg * 4 + r][pqr * 64 + unit] = (u16)(hv >> (r * 16));
        }
      }
    }
    __syncthreads();

    if (s > 0) {
#pragma unroll
      for (int ks2 = 0; ks2 < 4; ++ks2) {
        int ks = kh * 4 + ks2;
        uint4 av = *reinterpret_cast<const uint4*>(&Ah[col][ks * 32 + quad * 8]);
        short8 a8 = __builtin_bit_cast(short8, av);
#pragma unroll
        for (int gi = 0; gi < 4; ++gi)
          acc[gi] = __builtin_amdgcn_mfma_f32_16x16x32_bf16(
              a8, __builtin_bit_cast(short8, Bs[(ks * 16 + ub * 4 + gi) * 64 + l]), acc[gi], 0, 0, 0);
      }
      if (kh == 1)
#pragma unroll
        for (int gi = 0; gi < 4; ++gi) Pt[ub * 4 + gi][l] = acc[gi];
    }
    __syncthreads();

    if (kh == 0) {
      if (s > 0)
#pragma unroll
        for (int gi = 0; gi < 4; ++gi) acc[gi] += Pt[ub * 4 + gi][l];
      u16 hbf[4];
#pragma unroll
      for (int r = 0; r < 4; ++r) {
        float gi_ = acc[0][r] + b2f((u16)(gxv[r].x & 0xffff));
        float gf_ = acc[1][r] + b2f((u16)(gxv[r].x >> 16));
        float gg_ = acc[2][r] + b2f((u16)(gxv[r].y & 0xffff));
        float go_ = acc[3][r] + b2f((u16)(gxv[r].y >> 16));
        c[r] = sigf(gf_) * c[r] + sigf(gi_) * tanh_f(gg_);
        float h = sigf(go_) * tanh_f(c[r]);
        hbf[r] = f2bf(h);
        Ah[m0 + r][u] = hbf[r];
        out[((size_t)(bg * 16 + m0 + r) * Sn + t) * HIDn + dir * Hn + u] = hbf[r];
      }
      u64 hpack = (u64)hbf[0] | ((u64)hbf[1] << 16) | ((u64)hbf[2] << 32) | ((u64)hbf[3] << 48);
      __hip_atomic_store(mine + (size_t)s * 256 + uq * 4 + quad, hpack,
                         __ATOMIC_RELAXED, __HIP_MEMORY_SCOPE_AGENT);
    }
  }
}

// ---------------- FC: one wave per (b,t), bf16 input rows ----------------
__global__ __launch_bounds__(64) void fc_kernel(const u16* __restrict__ out1,
                                                const float* __restrict__ fcw,
                                                const float* __restrict__ fcb,
                                                float* __restrict__ feats) {
  const int bs = blockIdx.x;
  const int l = threadIdx.x;
  const u16* row = out1 + (size_t)bs * HIDn;
  uint4 rv = *reinterpret_cast<const uint4*>(row + l * 8);
  float v[8];
  v[0] = bflo(rv.x); v[1] = bfhi(rv.x);
  v[2] = bflo(rv.y); v[3] = bfhi(rv.y);
  v[4] = bflo(rv.z); v[5] = bfhi(rv.z);
  v[6] = bflo(rv.w); v[7] = bfhi(rv.w);
#pragma unroll
  for (int tag = 0; tag < Tn; ++tag) {
    const float* w = fcw + tag * HIDn + l * 8;
    float4 w0 = *reinterpret_cast<const float4*>(w);
    float4 w1 = *reinterpret_cast<const float4*>(w + 4);
    float acc = v[0] * w0.x + v[1] * w0.y + v[2] * w0.z + v[3] * w0.w
              + v[4] * w1.x + v[5] * w1.y + v[6] * w1.z + v[7] * w1.w;
#pragma unroll
    for (int off = 32; off; off >>= 1) acc += __shfl_xor(acc, off);
    if (l == 0) feats[bs * Tn + tag] = acc + fcb[tag];
  }
}

// ---------------- CRF forward + gold, one wave per batch ----------------
__global__ __launch_bounds__(64) void crf_kernel(const float* __restrict__ feats,
                                                 const int* __restrict__ tags,
                                                 const int* __restrict__ lens,
                                                 const float* __restrict__ trans,
                                                 float* __restrict__ scores) {
  const int b = blockIdx.x;
  const int j = threadIdx.x;
  const int jj = j < Tn ? j : Tn - 1;
  const int len = lens[b];

  float trc[Tn];
#pragma unroll
  for (int i = 0; i < Tn; ++i) trc[i] = trans[i * Tn + jj];
  const float trS = trans[jj * Tn + STOP_T];

  float alpha = (j == START_T) ? 0.0f : NEGV;
  const float* fb = feats + (size_t)b * Sn * Tn;

  for (int t = 0; t < Sn; ++t) {
    float f = (j < Tn) ? fb[t * Tn + j] : 0.0f;
    float v[Tn];
    float m = -3.0e38f;
#pragma unroll
    for (int i = 0; i < Tn; ++i) {
      float ai = __shfl(alpha, i);
      v[i] = ai + trc[i];
      m = fmaxf(m, v[i]);
    }
    float ssum = 0.0f;
#pragma unroll
    for (int i = 0; i < Tn; ++i) ssum += __expf(v[i] - m);
    float newa = m + __logf(ssum) + f;
    if (t < len && j < Tn) alpha = newa;
  }

  float val = (j < Tn) ? alpha + trS : -3.0e38f;
  float m = val;
#pragma unroll
  for (int off = 32; off; off >>= 1) m = fmaxf(m, __shfl_xor(m, off));
  float se = (j < Tn) ? __expf(val - m) : 0.0f;
#pragma unroll
  for (int off = 32; off; off >>= 1) se += __shfl_xor(se, off);
  float fscore = m + __logf(se);

  const int* tg = tags + b * Sn;
  float part = 0.0f;
  for (int q = 0; q < 8; ++q) {
    int s0 = j * 8 + q;
    if (s0 < Sn - 1 && (s0 + 1) < len) {
      int ta = tg[s0], tb = tg[s0 + 1];
      part += trans[ta * Tn + tb] + fb[s0 * Tn + tb];
    }
  }
#pragma unroll
  for (int off = 32; off; off >>= 1) part += __shfl_xor(part, off);

  if (j == 0) {
    int t0 = tg[0];
    int tl = tg[len - 1];
    float gold = trans[START_T * Tn + t0] + fb[0 * Tn + t0] + part + trans[tl * Tn + STOP_T];
    scores[b] = fscore - gold;
  }
}

__global__ void finalize_kernel(const float* __restrict__ scores, float* __restrict__ out) {
  int l = threadIdx.x;
  float v = scores[l];
#pragma unroll
  for (int off = 32; off; off >>= 1) v += __shfl_xor(v, off);
  if (l == 0) out[0] = v / 64.0f;
}

extern "C" void kernel_launch(void* const* d_in, const int* in_sizes, int n_in,
                              void* d_out, int out_size, void* d_ws, size_t ws_size,
                              hipStream_t stream) {
  const int* sent = (const int*)d_in[0];
  const int* tags = (const int*)d_in[1];
  const int* lens = (const int*)d_in[2];
  const float* emb = (const float*)d_in[3];
  const float* wih0 = (const float*)d_in[4];
  const float* whh0 = (const float*)d_in[5];
  const float* bih0 = (const float*)d_in[6];
  const float* bhh0 = (const float*)d_in[7];
  const float* wih1 = (const float*)d_in[8];
  const float* whh1 = (const float*)d_in[9];
  const float* bih1 = (const float*)d_in[10];
  const float* bhh1 = (const float*)d_in[11];
  const float* fcw = (const float*)d_in[12];
  const float* fcb = (const float*)d_in[13];
  const float* trans = (const float*)d_in[14];

  // workspace (~206 MB)
  char* ws = (char*)d_ws;
  u16* outb = (u16*)ws;                                  // 33,554,432 B
  u16* gx2 = (u16*)(ws + 33554432);                      // 134,217,728 B
  float* feats = (float*)gx2;                            // aliases gx2 (dead before fc)
  char* p = ws + 33554432 + 134217728;
  u64* hx = (u64*)p;                    p += 33554432;   // [8][4][512][256] u64
  float* scores = (float*)p;            p += 256;
  float* bias0 = (float*)p;             p += 8192;
  float* bias1 = (float*)p;             p += 8192;
  u16* wifrag0 = (u16*)p;               p += 1048576;    // 524,288 u16
  u16* wifrag1 = (u16*)p;               p += 2097152;    // 1,048,576 u16
  u16* wfrag0 = (u16*)p;                p += 1048576;
  u16* wfrag1 = (u16*)p;                p += 1048576;

  prep_kernel<<<2048, 256, 0, stream>>>(wih0, whh0, bih0, bhh0, wih1, whh1, bih1, bhh1,
                                        wifrag0, wifrag1, wfrag0, wfrag1, bias0, bias1);

  dim3 ggrid(Mn / 64, 2);
  hipMemsetAsync(hx, 0xFF, 33554432, stream);
  gemm_ih<8, true><<<ggrid, 256, 0, stream>>>(emb, sent, (const uint4*)wifrag0, bias0, gx2);
  lstm_recur_mfma<<<32, 512, 0, stream>>>((const uint4*)wfrag0, gx2, hx, outb);
  hipMemsetAsync(hx, 0xFF, 33554432, stream);
  gemm_ih<16, false><<<ggrid, 256, 0, stream>>>(outb, nullptr, (const uint4*)wifrag1, bias1, gx2);
  lstm_recur_mfma<<<32, 512, 0, stream>>>((const uint4*)wfrag1, gx2, hx, outb);

  fc_kernel<<<Mn, 64, 0, stream>>>(outb, fcw, fcb, feats);
  crf_kernel<<<Bn, 64, 0, stream>>>(feats, tags, lens, trans, scores);
  finalize_kernel<<<1, 64, 0, stream>>>(scores, (float*)d_out);
}